// Round 14
// baseline (225.949 us; speedup 1.0000x reference)
//
#include <hip/hip_runtime.h>
#include <cstdint>

#define NN 100000
#define DD 128
#define EE 1000000
#define NBK 782         // buckets of 256 rows over 2*NN combined rows
#define SLOT 3008       // fixed edata slot per bucket (mean 2560, +8.8 sigma)
#define CHUNK 2048      // edges per multisplit block (R14 probe: was 8192)
#define BN_EPS 1e-5f

typedef __attribute__((ext_vector_type(4))) float f32x4;
typedef __attribute__((ext_vector_type(8))) short bf16x8;
typedef __attribute__((ext_vector_type(8))) unsigned short u16x8;

__device__ __forceinline__ unsigned short f2bf(float f) {
  union { float f; unsigned u; } c; c.f = f;
  unsigned u = c.u;
  return (unsigned short)((u + 0x7FFFu + ((u >> 16) & 1u)) >> 16);  // RNE
}
__device__ __forceinline__ float bf2f(unsigned short h) {
  union { unsigned u; float f; } c; c.u = ((unsigned)h) << 16;
  return c.f;
}
__device__ __forceinline__ void gld16(const void* g, void* l) {
  __builtin_amdgcn_global_load_lds(
      (const __attribute__((address_space(1))) unsigned int*)g,
      (__attribute__((address_space(3))) unsigned int*)l, 16, 0, 0);
}

// ---------------------------------------------------------------- init: slot cursors + stats zero
__global__ __launch_bounds__(256) void init_k(int* __restrict__ gCur,
                                              float* __restrict__ stats) {
  int g = blockIdx.x * 256 + threadIdx.x;  // 5 blocks = 1280
  if (g < 1024) gCur[g] = g * SLOT;
  else if (g < 1280) stats[g - 1024] = 0.f;
}

// ---------------------------------------------------------------- multisplit scatter + fused xcvt/packB
__global__ __launch_bounds__(256) void bscat_k(const int* __restrict__ lei,
                                               const int* __restrict__ gei,
                                               int* __restrict__ gCur,
                                               unsigned* __restrict__ edata,
                                               const float* __restrict__ x,
                                               char* __restrict__ xbD,
                                               const float* __restrict__ W1,
                                               const float* __restrict__ W2L,
                                               const float* __restrict__ W2G,
                                               unsigned short* __restrict__ Bw) {
  __shared__ int lofs[1025];
  __shared__ int lcur[1024];
  __shared__ int gbase[1024];
  __shared__ unsigned short bid[CHUNK];
  __shared__ unsigned stage[CHUNK];
  __shared__ int wsum[4];
  int t = threadIdx.x;
#pragma unroll
  for (int k = 0; k < 4; ++k) lofs[t * 4 + k] = 0;

  // ---- fused xcvt: x -> bf16 dense [NN][256B]  (grid-stride, hides under LDS phases)
  for (int i8 = blockIdx.x * 256 + t; i8 < NN * DD / 8; i8 += gridDim.x * 256) {
    int row = i8 >> 4, c = i8 & 15;
    const float* src = x + (size_t)row * DD + c * 8;
    f32x4 v0 = *(const f32x4*)src;
    f32x4 v1 = *(const f32x4*)(src + 4);
    u16x8 h;
    h[0] = f2bf(v0[0]); h[1] = f2bf(v0[1]); h[2] = f2bf(v0[2]); h[3] = f2bf(v0[3]);
    h[4] = f2bf(v1[0]); h[5] = f2bf(v1[1]); h[6] = f2bf(v1[2]); h[7] = f2bf(v1[3]);
    *(u16x8*)(xbD + (size_t)row * 256 + c * 16) = h;
  }
  // ---- fused packB: B [128][384] bf16
  for (int g = blockIdx.x * 256 + t; g < DD * 384; g += gridDim.x * 256) {
    int j = g / 384, k = g - j * 384;
    const float* W = (k < DD) ? W1 : ((k < 2 * DD) ? W2L : W2G);
    Bw[g] = f2bf(W[j * DD + (k & (DD - 1))]);
  }

  // ---- original multisplit ----
  int base = blockIdx.x * CHUNK;
  int cnt = 2 * EE - base; if (cnt > CHUNK) cnt = CHUNK;
  __syncthreads();
#pragma unroll 4
  for (int j = 0; j < CHUNK / 256; ++j) {
    int i = base + j * 256 + t;
    if (i < 2 * EE) {
      int grow = (i < EE) ? lei[i] : (NN + gei[i - EE]);
      atomicAdd(&lofs[grow >> 8], 1);
    }
  }
  __syncthreads();
  int v[4];
#pragma unroll
  for (int k = 0; k < 4; ++k) v[k] = lofs[t * 4 + k];
  int tot = v[0] + v[1] + v[2] + v[3];
  int lane = t & 63, wv = t >> 6;
  int inc = tot;
  for (int d = 1; d < 64; d <<= 1) { int u = __shfl_up(inc, d); if (lane >= d) inc += u; }
  if (lane == 63) wsum[wv] = inc;
  __syncthreads();
  int woff = 0;
#pragma unroll
  for (int w = 0; w < 4; ++w) if (w < wv) woff += wsum[w];
  int run = woff + inc - tot;
#pragma unroll
  for (int k = 0; k < 4; ++k) { lofs[t * 4 + k] = run; lcur[t * 4 + k] = run; run += v[k]; }
  if (t == 0) lofs[1024] = cnt;
  __syncthreads();
#pragma unroll 4
  for (int j = 0; j < CHUNK / 256; ++j) {
    int i = base + j * 256 + t;
    if (i < 2 * EE) {
      int grow, col;
      if (i < EE) { grow = lei[i]; col = lei[EE + i]; }
      else        { grow = NN + gei[i - EE]; col = gei[i]; }
      int b = grow >> 8;
      int pos = atomicAdd(&lcur[b], 1);
      stage[pos] = (unsigned)col | ((unsigned)(grow & 255) << 24);
      bid[pos] = (unsigned short)b;
    }
  }
  __syncthreads();
#pragma unroll
  for (int k = 0; k < 4; ++k) {
    int b = t * 4 + k;
    int c = lofs[b + 1] - lofs[b];
    if (c > 0) gbase[b] = atomicAdd(&gCur[b], c);
  }
  __syncthreads();
  for (int i = t; i < cnt; i += 256) {
    int b = bid[i];
    edata[gbase[b] + (i - lofs[b])] = stage[i];
  }
}

// ---------------------------------------------------------------- per-half-bucket LDS CSR + gather (R10 version)
__global__ __launch_bounds__(256) void bgather_k(const char* __restrict__ xbD,
                                                 const int* __restrict__ gCur,
                                                 const unsigned* __restrict__ edata,
                                                 unsigned short* __restrict__ aggLb,
                                                 char* __restrict__ outD) {
  __shared__ int rowOff[129];
  __shared__ int rowCur[128];
  __shared__ unsigned colS[2048];
  __shared__ int wsum1;
  int t = threadIdx.x;
  int h = blockIdx.x, b = h >> 1, half = h & 1;
  int s0 = b * SLOT;
  int cnt = gCur[b] - s0;
  if (t < 128) rowCur[t] = 0;
  __syncthreads();
  for (int i = t; i < cnt; i += 256) {
    unsigned e = edata[s0 + i];
    unsigned r8 = e >> 24;
    if ((int)(r8 >> 7) == half) atomicAdd(&rowCur[r8 & 127], 1);
  }
  __syncthreads();
  int v = 0, inc = 0;
  if (t < 128) {
    v = rowCur[t];
    inc = v;
    int lane = t & 63;
    for (int d = 1; d < 64; d <<= 1) { int u = __shfl_up(inc, d); if (lane >= d) inc += u; }
    if (t == 63) wsum1 = inc;
  }
  __syncthreads();
  if (t < 128) {
    int excl = inc - v + ((t >> 6) ? wsum1 : 0);
    rowOff[t] = excl;
    if (t == 127) rowOff[128] = excl + v;
    rowCur[t] = excl;
  }
  __syncthreads();
  for (int i = t; i < cnt; i += 256) {
    unsigned e = edata[s0 + i];
    unsigned r8 = e >> 24;
    if ((int)(r8 >> 7) == half) {
      int pos = atomicAdd(&rowCur[r8 & 127], 1);
      if (pos < 2048) colS[pos] = e & 0xFFFFFFu;
    }
  }
  __syncthreads();
  int g16 = t >> 4, lane16 = t & 15;
  int rowsbase = b * 256 + half * 128;
  for (int r = g16; r < 128; r += 16) {
    int grow = rowsbase + r;
    if (grow >= 2 * NN) break;
    int e0 = rowOff[r], e1 = rowOff[r + 1];
    float a[8] = {0.f, 0.f, 0.f, 0.f, 0.f, 0.f, 0.f, 0.f};
    for (int i = e0; i < e1; ++i) {
      unsigned col = colS[i];
      u16x8 x8 = *(const u16x8*)(xbD + (size_t)col * 256 + lane16 * 16);
#pragma unroll
      for (int j = 0; j < 8; ++j) a[j] += bf2f(x8[j]);
    }
    u16x8 hv;
#pragma unroll
    for (int j = 0; j < 8; ++j) hv[j] = f2bf(a[j]);
    if (grow < NN)
      *(u16x8*)(aggLb + (size_t)grow * DD + lane16 * 8) = hv;
    else
      *(u16x8*)(outD + (size_t)(grow - NN) * 512 + 256 + lane16 * 16) = hv;
  }
}

// ---------------------------------------------------------------- GEMM BK=32, 4 blocks/CU, bf16 C over aggLb (R10 version)
__global__ __launch_bounds__(256, 4) void gemm_k(
    const char* __restrict__ xbD, unsigned short* __restrict__ aggLb,
    const char* __restrict__ outD, const unsigned short* __restrict__ Bw,
    float* __restrict__ stats) {
  __shared__ unsigned short Asm[2][128 * 32];  // 8KB each
  __shared__ unsigned short Bsm[2][128 * 32];
  __shared__ float red[4][256];
  int t = threadIdx.x, wave = t >> 6, lane = t & 63;
  int row0 = blockIdx.x * 128;

  f32x4 acc[2][8];
#pragma unroll
  for (int mi = 0; mi < 2; ++mi)
#pragma unroll
    for (int ni = 0; ni < 8; ++ni) acc[mi][ni] = (f32x4){0.f, 0.f, 0.f, 0.f};

  // rows are 64B (4 chunks of 16B); swizzle chunk c -> c ^ ((r>>1)&3).
  // LDS dest linear: 16B per thread slot -> short index (i*256+wave*64)*8.
  auto STAGE = [&](int s, int b) {
#pragma unroll
    for (int i = 0; i < 2; ++i) {
      int flat = t + i * 256, r = flat >> 2, c = flat & 3;
      int cs = c ^ ((r >> 1) & 3);
      int rr = row0 + r; rr = (rr < NN) ? rr : (NN - 1);
      const char* src;
      if (s < 4)      src = xbD + (size_t)rr * 256 + (s & 3) * 64 + cs * 16;
      else if (s < 8) src = (const char*)aggLb + (size_t)rr * 256 + (s - 4) * 64 + cs * 16;
      else            src = outD + (size_t)rr * 512 + 256 + (s - 8) * 64 + cs * 16;
      gld16(src, &Asm[b][(size_t)(i * 256 + wave * 64) * 8]);
    }
#pragma unroll
    for (int i = 0; i < 2; ++i) {
      int flat = t + i * 256, n = flat >> 2, c = flat & 3;
      int cs = c ^ ((n >> 1) & 3);
      const char* src = (const char*)Bw + (size_t)n * 768 + s * 64 + cs * 16;
      gld16(src, &Bsm[b][(size_t)(i * 256 + wave * 64) * 8]);
    }
  };

  auto COMPUTE = [&](int b) {
    int mr = lane & 15, kq = lane >> 4;
    int r0 = wave * 32 + mr, r1 = r0 + 16;
    bf16x8 a0 = *(const bf16x8*)&Asm[b][((size_t)r0 * 4 + (kq ^ ((r0 >> 1) & 3))) * 8];
    bf16x8 a1 = *(const bf16x8*)&Asm[b][((size_t)r1 * 4 + (kq ^ ((r1 >> 1) & 3))) * 8];
#pragma unroll
    for (int ni = 0; ni < 8; ++ni) {
      int nr = ni * 16 + mr;
      bf16x8 bb = *(const bf16x8*)&Bsm[b][((size_t)nr * 4 + (kq ^ ((nr >> 1) & 3))) * 8];
      acc[0][ni] = __builtin_amdgcn_mfma_f32_16x16x32_bf16(a0, bb, acc[0][ni], 0, 0, 0);
      acc[1][ni] = __builtin_amdgcn_mfma_f32_16x16x32_bf16(a1, bb, acc[1][ni], 0, 0, 0);
    }
  };

  STAGE(0, 0);
  __syncthreads();
#pragma unroll
  for (int s = 0; s < 12; ++s) {
    int b = s & 1;
    if (s < 11) STAGE(s + 1, b ^ 1);
    COMPUTE(b);
    __syncthreads();
  }

  // epilogue: C/D layout col=lane&15, row=(lane>>4)*4+reg; C -> bf16 over aggLb (own rows)
  int colbase = lane & 15, rbase = (lane >> 4) * 4;
#pragma unroll
  for (int ni = 0; ni < 8; ++ni) {
    int col = ni * 16 + colbase;
    float s = 0.f, q = 0.f;
#pragma unroll
    for (int mi = 0; mi < 2; ++mi)
#pragma unroll
      for (int r = 0; r < 4; ++r) {
        int row = row0 + wave * 32 + mi * 16 + rbase + r;
        float v = acc[mi][ni][r];
        if (row < NN) {
          aggLb[(size_t)row * DD + col] = f2bf(v);
          s += v; q += v * v;
        }
      }
    s += __shfl_xor(s, 16); s += __shfl_xor(s, 32);
    q += __shfl_xor(q, 16); q += __shfl_xor(q, 32);
    if (lane < 16) { red[wave][col] = s; red[wave][128 + col] = q; }
  }
  __syncthreads();
  float v = red[0][t & 255] + red[1][t & 255] + red[2][t & 255] + red[3][t & 255];
  atomicAdd(&stats[t & 255], v);
}

// ---------------------------------------------------------------- BN finalize + apply + ReLU (fused, R10 version)
__global__ __launch_bounds__(256) void bn_relu_k(const unsigned short* __restrict__ Cb,
                                                 const float* __restrict__ stats,
                                                 const float* __restrict__ gamma,
                                                 const float* __restrict__ beta,
                                                 float* __restrict__ out) {
  __shared__ float sc[128], sh[128];
  int t = threadIdx.x;
  if (t < 128) {
    float mean = stats[t] * (1.f / NN);
    float var = stats[DD + t] * (1.f / NN) - mean * mean;
    float inv = rsqrtf(var + BN_EPS);
    float s = gamma[t] * inv;
    sc[t] = s;
    sh[t] = beta[t] - mean * s;
  }
  __syncthreads();
  int i8 = blockIdx.x * 256 + t;  // 1.6M exact
  int row = i8 >> 4, c = i8 & 15;
  u16x8 h = *(const u16x8*)(Cb + (size_t)row * DD + c * 8);
  int f0 = c * 8;
  f32x4 o0, o1;
#pragma unroll
  for (int j = 0; j < 4; ++j) {
    o0[j] = fmaxf(bf2f(h[j]) * sc[f0 + j] + sh[f0 + j], 0.f);
    o1[j] = fmaxf(bf2f(h[4 + j]) * sc[f0 + 4 + j] + sh[f0 + 4 + j], 0.f);
  }
  float* dst = out + (size_t)row * DD + f0;
  *(f32x4*)dst = o0;
  *(f32x4*)(dst + 4) = o1;
}

// ---------------------------------------------------------------- launch
extern "C" void kernel_launch(void* const* d_in, const int* in_sizes, int n_in,
                              void* d_out, int out_size, void* d_ws, size_t ws_size,
                              hipStream_t stream) {
  const float* x     = (const float*)d_in[0];
  const int*   lei   = (const int*)d_in[1];
  const int*   gei   = (const int*)d_in[2];
  const float* W1    = (const float*)d_in[3];
  const float* W2L   = (const float*)d_in[4];
  const float* W2G   = (const float*)d_in[5];
  const float* gamma = (const float*)d_in[6];
  const float* beta  = (const float*)d_in[7];
  float* out = (float*)d_out;
  char* outD = (char*)d_out;  // aggG lives in odd 256B halves of out rows

  char* w = (char*)d_ws;
  size_t o = 0;
  char* xbD = (char*)(w + o); o += (size_t)NN * 256;                           // 25.6MB dense bf16 x
  unsigned short* aggLb = (unsigned short*)(w + o); o += (size_t)NN * DD * 2;  // 25.6MB (later holds bf16 C)
  unsigned* edata = (unsigned*)(w + o); o += (size_t)NBK * SLOT * 4;           // 9.41MB
  int* gCur = (int*)(w + o); o += 1024 * 4;
  unsigned short* Bw = (unsigned short*)(w + o); o += (size_t)DD * 384 * 2;    // 96KB
  float* stats = (float*)(w + o); o += 1024;   // total ~60.71MB

  init_k<<<5, 256, 0, stream>>>(gCur, stats);

  int nbc = (2 * EE + CHUNK - 1) / CHUNK;  // 977
  bscat_k<<<nbc, 256, 0, stream>>>(lei, gei, gCur, edata, x, xbD, W1, W2L, W2G, Bw);
  bgather_k<<<2 * NBK, 256, 0, stream>>>(xbD, gCur, edata, aggLb, outD);

  gemm_k<<<(NN + 127) / 128, 256, 0, stream>>>(xbD, aggLb, outD, Bw, stats);
  bn_relu_k<<<(NN * DD / 8) / 256, 256, 0, stream>>>(aggLb, stats, gamma, beta, out);
}

// Round 15
// 192.385 us; speedup vs baseline: 1.1745x; 1.1745x over previous
//
#include <hip/hip_runtime.h>
#include <cstdint>

#define NN 100000
#define DD 128
#define EE 1000000
#define NBK 782         // buckets of 256 rows over 2*NN combined rows
#define SLOT 3008       // fixed edata slot per bucket (mean 2560, +8.8 sigma)
#define CHUNK 8192      // edges per multisplit block (R14 probe confirmed optimum)
#define BN_EPS 1e-5f

typedef __attribute__((ext_vector_type(4))) float f32x4;
typedef __attribute__((ext_vector_type(8))) short bf16x8;
typedef __attribute__((ext_vector_type(8))) unsigned short u16x8;

__device__ __forceinline__ unsigned short f2bf(float f) {
  union { float f; unsigned u; } c; c.f = f;
  unsigned u = c.u;
  return (unsigned short)((u + 0x7FFFu + ((u >> 16) & 1u)) >> 16);  // RNE
}
__device__ __forceinline__ float bf2f(unsigned short h) {
  union { unsigned u; float f; } c; c.u = ((unsigned)h) << 16;
  return c.f;
}
__device__ __forceinline__ void gld16(const void* g, void* l) {
  __builtin_amdgcn_global_load_lds(
      (const __attribute__((address_space(1))) unsigned int*)g,
      (__attribute__((address_space(3))) unsigned int*)l, 16, 0, 0);
}

// ---------------------------------------------------------------- init: slot cursors + stats zero
__global__ __launch_bounds__(256) void init_k(int* __restrict__ gCur,
                                              float* __restrict__ stats) {
  int g = blockIdx.x * 256 + threadIdx.x;  // 5 blocks = 1280
  if (g < 1024) gCur[g] = g * SLOT;
  else if (g < 1280) stats[g - 1024] = 0.f;
}

// ---------------------------------------------------------------- multisplit scatter + fused xcvt/packB
__global__ __launch_bounds__(256) void bscat_k(const int* __restrict__ lei,
                                               const int* __restrict__ gei,
                                               int* __restrict__ gCur,
                                               unsigned* __restrict__ edata,
                                               const float* __restrict__ x,
                                               char* __restrict__ xbD,
                                               const float* __restrict__ W1,
                                               const float* __restrict__ W2L,
                                               const float* __restrict__ W2G,
                                               unsigned short* __restrict__ Bw) {
  __shared__ int lofs[1025];
  __shared__ int lcur[1024];
  __shared__ int gbase[1024];
  __shared__ unsigned short bid[CHUNK];
  __shared__ unsigned stage[CHUNK];
  __shared__ int wsum[4];
  int t = threadIdx.x;
#pragma unroll
  for (int k = 0; k < 4; ++k) lofs[t * 4 + k] = 0;

  // ---- fused xcvt: x -> bf16 dense [NN][256B]  (grid-stride, hides under LDS phases)
  for (int i8 = blockIdx.x * 256 + t; i8 < NN * DD / 8; i8 += gridDim.x * 256) {
    int row = i8 >> 4, c = i8 & 15;
    const float* src = x + (size_t)row * DD + c * 8;
    f32x4 v0 = *(const f32x4*)src;
    f32x4 v1 = *(const f32x4*)(src + 4);
    u16x8 h;
    h[0] = f2bf(v0[0]); h[1] = f2bf(v0[1]); h[2] = f2bf(v0[2]); h[3] = f2bf(v0[3]);
    h[4] = f2bf(v1[0]); h[5] = f2bf(v1[1]); h[6] = f2bf(v1[2]); h[7] = f2bf(v1[3]);
    *(u16x8*)(xbD + (size_t)row * 256 + c * 16) = h;
  }
  // ---- fused packB: B [128][384] bf16
  for (int g = blockIdx.x * 256 + t; g < DD * 384; g += gridDim.x * 256) {
    int j = g / 384, k = g - j * 384;
    const float* W = (k < DD) ? W1 : ((k < 2 * DD) ? W2L : W2G);
    Bw[g] = f2bf(W[j * DD + (k & (DD - 1))]);
  }

  // ---- original multisplit ----
  int base = blockIdx.x * CHUNK;
  int cnt = 2 * EE - base; if (cnt > CHUNK) cnt = CHUNK;
  __syncthreads();
#pragma unroll 4
  for (int j = 0; j < CHUNK / 256; ++j) {
    int i = base + j * 256 + t;
    if (i < 2 * EE) {
      int grow = (i < EE) ? lei[i] : (NN + gei[i - EE]);
      atomicAdd(&lofs[grow >> 8], 1);
    }
  }
  __syncthreads();
  int v[4];
#pragma unroll
  for (int k = 0; k < 4; ++k) v[k] = lofs[t * 4 + k];
  int tot = v[0] + v[1] + v[2] + v[3];
  int lane = t & 63, wv = t >> 6;
  int inc = tot;
  for (int d = 1; d < 64; d <<= 1) { int u = __shfl_up(inc, d); if (lane >= d) inc += u; }
  if (lane == 63) wsum[wv] = inc;
  __syncthreads();
  int woff = 0;
#pragma unroll
  for (int w = 0; w < 4; ++w) if (w < wv) woff += wsum[w];
  int run = woff + inc - tot;
#pragma unroll
  for (int k = 0; k < 4; ++k) { lofs[t * 4 + k] = run; lcur[t * 4 + k] = run; run += v[k]; }
  if (t == 0) lofs[1024] = cnt;
  __syncthreads();
#pragma unroll 4
  for (int j = 0; j < CHUNK / 256; ++j) {
    int i = base + j * 256 + t;
    if (i < 2 * EE) {
      int grow, col;
      if (i < EE) { grow = lei[i]; col = lei[EE + i]; }
      else        { grow = NN + gei[i - EE]; col = gei[i]; }
      int b = grow >> 8;
      int pos = atomicAdd(&lcur[b], 1);
      stage[pos] = (unsigned)col | ((unsigned)(grow & 255) << 24);
      bid[pos] = (unsigned short)b;
    }
  }
  __syncthreads();
#pragma unroll
  for (int k = 0; k < 4; ++k) {
    int b = t * 4 + k;
    int c = lofs[b + 1] - lofs[b];
    if (c > 0) gbase[b] = atomicAdd(&gCur[b], c);
  }
  __syncthreads();
  for (int i = t; i < cnt; i += 256) {
    int b = bid[i];
    edata[gbase[b] + (i - lofs[b])] = stage[i];
  }
}

// ---------------------------------------------------------------- per-half-bucket LDS CSR + gather
// XCD pair co-location: g -> b=(g>>4)*8+(g&7), half=(g>>3)&1; the two blocks
// of bucket b are 8 apart (same XCD slot under mod-8 round-robin) so the
// second slot read hits that XCD's L2.
__global__ __launch_bounds__(256) void bgather_k(const char* __restrict__ xbD,
                                                 const int* __restrict__ gCur,
                                                 const unsigned* __restrict__ edata,
                                                 unsigned short* __restrict__ aggLb,
                                                 char* __restrict__ outD) {
  __shared__ int rowOff[129];
  __shared__ int rowCur[128];
  __shared__ unsigned colS[2048];
  __shared__ int wsum1;
  int t = threadIdx.x;
  int g = blockIdx.x;
  int b = (g >> 4) * 8 + (g & 7);
  int half = (g >> 3) & 1;
  if (b >= NBK) return;
  int s0 = b * SLOT;
  int cnt = gCur[b] - s0;
  if (t < 128) rowCur[t] = 0;
  __syncthreads();
  for (int i = t; i < cnt; i += 256) {
    unsigned e = edata[s0 + i];
    unsigned r8 = e >> 24;
    if ((int)(r8 >> 7) == half) atomicAdd(&rowCur[r8 & 127], 1);
  }
  __syncthreads();
  int v = 0, inc = 0;
  if (t < 128) {
    v = rowCur[t];
    inc = v;
    int lane = t & 63;
    for (int d = 1; d < 64; d <<= 1) { int u = __shfl_up(inc, d); if (lane >= d) inc += u; }
    if (t == 63) wsum1 = inc;
  }
  __syncthreads();
  if (t < 128) {
    int excl = inc - v + ((t >> 6) ? wsum1 : 0);
    rowOff[t] = excl;
    if (t == 127) rowOff[128] = excl + v;
    rowCur[t] = excl;
  }
  __syncthreads();
  for (int i = t; i < cnt; i += 256) {
    unsigned e = edata[s0 + i];
    unsigned r8 = e >> 24;
    if ((int)(r8 >> 7) == half) {
      int pos = atomicAdd(&rowCur[r8 & 127], 1);
      if (pos < 2048) colS[pos] = e & 0xFFFFFFu;
    }
  }
  __syncthreads();
  int g16 = t >> 4, lane16 = t & 15;
  int rowsbase = b * 256 + half * 128;
  for (int r = g16; r < 128; r += 16) {
    int grow = rowsbase + r;
    if (grow >= 2 * NN) break;
    int e0 = rowOff[r], e1 = rowOff[r + 1];
    float a[8] = {0.f, 0.f, 0.f, 0.f, 0.f, 0.f, 0.f, 0.f};
    for (int i = e0; i < e1; ++i) {
      unsigned col = colS[i];
      u16x8 x8 = *(const u16x8*)(xbD + (size_t)col * 256 + lane16 * 16);
#pragma unroll
      for (int j = 0; j < 8; ++j) a[j] += bf2f(x8[j]);
    }
    u16x8 hv;
#pragma unroll
    for (int j = 0; j < 8; ++j) hv[j] = f2bf(a[j]);
    if (grow < NN)
      *(u16x8*)(aggLb + (size_t)grow * DD + lane16 * 8) = hv;
    else
      *(u16x8*)(outD + (size_t)(grow - NN) * 512 + 256 + lane16 * 16) = hv;
  }
}

// ---------------------------------------------------------------- GEMM BK=32, 4 blocks/CU, bf16 C over aggLb
__global__ __launch_bounds__(256, 4) void gemm_k(
    const char* __restrict__ xbD, unsigned short* __restrict__ aggLb,
    const char* __restrict__ outD, const unsigned short* __restrict__ Bw,
    float* __restrict__ stats) {
  __shared__ unsigned short Asm[2][128 * 32];  // 8KB each
  __shared__ unsigned short Bsm[2][128 * 32];
  __shared__ float red[4][256];
  int t = threadIdx.x, wave = t >> 6, lane = t & 63;
  int row0 = blockIdx.x * 128;

  f32x4 acc[2][8];
#pragma unroll
  for (int mi = 0; mi < 2; ++mi)
#pragma unroll
    for (int ni = 0; ni < 8; ++ni) acc[mi][ni] = (f32x4){0.f, 0.f, 0.f, 0.f};

  // rows are 64B (4 chunks of 16B); swizzle chunk c -> c ^ ((r>>1)&3).
  // LDS dest linear: 16B per thread slot -> short index (i*256+wave*64)*8.
  auto STAGE = [&](int s, int b) {
#pragma unroll
    for (int i = 0; i < 2; ++i) {
      int flat = t + i * 256, r = flat >> 2, c = flat & 3;
      int cs = c ^ ((r >> 1) & 3);
      int rr = row0 + r; rr = (rr < NN) ? rr : (NN - 1);
      const char* src;
      if (s < 4)      src = xbD + (size_t)rr * 256 + (s & 3) * 64 + cs * 16;
      else if (s < 8) src = (const char*)aggLb + (size_t)rr * 256 + (s - 4) * 64 + cs * 16;
      else            src = outD + (size_t)rr * 512 + 256 + (s - 8) * 64 + cs * 16;
      gld16(src, &Asm[b][(size_t)(i * 256 + wave * 64) * 8]);
    }
#pragma unroll
    for (int i = 0; i < 2; ++i) {
      int flat = t + i * 256, n = flat >> 2, c = flat & 3;
      int cs = c ^ ((n >> 1) & 3);
      const char* src = (const char*)Bw + (size_t)n * 768 + s * 64 + cs * 16;
      gld16(src, &Bsm[b][(size_t)(i * 256 + wave * 64) * 8]);
    }
  };

  auto COMPUTE = [&](int b) {
    int mr = lane & 15, kq = lane >> 4;
    int r0 = wave * 32 + mr, r1 = r0 + 16;
    bf16x8 a0 = *(const bf16x8*)&Asm[b][((size_t)r0 * 4 + (kq ^ ((r0 >> 1) & 3))) * 8];
    bf16x8 a1 = *(const bf16x8*)&Asm[b][((size_t)r1 * 4 + (kq ^ ((r1 >> 1) & 3))) * 8];
#pragma unroll
    for (int ni = 0; ni < 8; ++ni) {
      int nr = ni * 16 + mr;
      bf16x8 bb = *(const bf16x8*)&Bsm[b][((size_t)nr * 4 + (kq ^ ((nr >> 1) & 3))) * 8];
      acc[0][ni] = __builtin_amdgcn_mfma_f32_16x16x32_bf16(a0, bb, acc[0][ni], 0, 0, 0);
      acc[1][ni] = __builtin_amdgcn_mfma_f32_16x16x32_bf16(a1, bb, acc[1][ni], 0, 0, 0);
    }
  };

  STAGE(0, 0);
  __syncthreads();
#pragma unroll
  for (int s = 0; s < 12; ++s) {
    int b = s & 1;
    if (s < 11) STAGE(s + 1, b ^ 1);
    COMPUTE(b);
    __syncthreads();
  }

  // epilogue: C/D layout col=lane&15, row=(lane>>4)*4+reg; C -> bf16 over aggLb (own rows)
  int colbase = lane & 15, rbase = (lane >> 4) * 4;
#pragma unroll
  for (int ni = 0; ni < 8; ++ni) {
    int col = ni * 16 + colbase;
    float s = 0.f, q = 0.f;
#pragma unroll
    for (int mi = 0; mi < 2; ++mi)
#pragma unroll
      for (int r = 0; r < 4; ++r) {
        int row = row0 + wave * 32 + mi * 16 + rbase + r;
        float v = acc[mi][ni][r];
        if (row < NN) {
          aggLb[(size_t)row * DD + col] = f2bf(v);
          s += v; q += v * v;
        }
      }
    s += __shfl_xor(s, 16); s += __shfl_xor(s, 32);
    q += __shfl_xor(q, 16); q += __shfl_xor(q, 32);
    if (lane < 16) { red[wave][col] = s; red[wave][128 + col] = q; }
  }
  __syncthreads();
  float v = red[0][t & 255] + red[1][t & 255] + red[2][t & 255] + red[3][t & 255];
  atomicAdd(&stats[t & 255], v);
}

// ---------------------------------------------------------------- BN finalize + apply + ReLU (fused)
__global__ __launch_bounds__(256) void bn_relu_k(const unsigned short* __restrict__ Cb,
                                                 const float* __restrict__ stats,
                                                 const float* __restrict__ gamma,
                                                 const float* __restrict__ beta,
                                                 float* __restrict__ out) {
  __shared__ float sc[128], sh[128];
  int t = threadIdx.x;
  if (t < 128) {
    float mean = stats[t] * (1.f / NN);
    float var = stats[DD + t] * (1.f / NN) - mean * mean;
    float inv = rsqrtf(var + BN_EPS);
    float s = gamma[t] * inv;
    sc[t] = s;
    sh[t] = beta[t] - mean * s;
  }
  __syncthreads();
  int i8 = blockIdx.x * 256 + t;  // 1.6M exact
  int row = i8 >> 4, c = i8 & 15;
  u16x8 h = *(const u16x8*)(Cb + (size_t)row * DD + c * 8);
  int f0 = c * 8;
  f32x4 o0, o1;
#pragma unroll
  for (int j = 0; j < 4; ++j) {
    o0[j] = fmaxf(bf2f(h[j]) * sc[f0 + j] + sh[f0 + j], 0.f);
    o1[j] = fmaxf(bf2f(h[4 + j]) * sc[f0 + 4 + j] + sh[f0 + 4 + j], 0.f);
  }
  float* dst = out + (size_t)row * DD + f0;
  *(f32x4*)dst = o0;
  *(f32x4*)(dst + 4) = o1;
}

// ---------------------------------------------------------------- launch
extern "C" void kernel_launch(void* const* d_in, const int* in_sizes, int n_in,
                              void* d_out, int out_size, void* d_ws, size_t ws_size,
                              hipStream_t stream) {
  const float* x     = (const float*)d_in[0];
  const int*   lei   = (const int*)d_in[1];
  const int*   gei   = (const int*)d_in[2];
  const float* W1    = (const float*)d_in[3];
  const float* W2L   = (const float*)d_in[4];
  const float* W2G   = (const float*)d_in[5];
  const float* gamma = (const float*)d_in[6];
  const float* beta  = (const float*)d_in[7];
  float* out = (float*)d_out;
  char* outD = (char*)d_out;  // aggG lives in odd 256B halves of out rows

  char* w = (char*)d_ws;
  size_t o = 0;
  char* xbD = (char*)(w + o); o += (size_t)NN * 256;                           // 25.6MB dense bf16 x
  unsigned short* aggLb = (unsigned short*)(w + o); o += (size_t)NN * DD * 2;  // 25.6MB (later holds bf16 C)
  unsigned* edata = (unsigned*)(w + o); o += (size_t)NBK * SLOT * 4;           // 9.41MB
  int* gCur = (int*)(w + o); o += 1024 * 4;
  unsigned short* Bw = (unsigned short*)(w + o); o += (size_t)DD * 384 * 2;    // 96KB
  float* stats = (float*)(w + o); o += 1024;   // total ~60.71MB

  init_k<<<5, 256, 0, stream>>>(gCur, stats);

  int nbc = (2 * EE + CHUNK - 1) / CHUNK;  // 245
  bscat_k<<<nbc, 256, 0, stream>>>(lei, gei, gCur, edata, x, xbD, W1, W2L, W2G, Bw);
  bgather_k<<<1568, 256, 0, stream>>>(xbD, gCur, edata, aggLb, outD);

  gemm_k<<<(NN + 127) / 128, 256, 0, stream>>>(xbD, aggLb, outD, Bw, stats);
  bn_relu_k<<<(NN * DD / 8) / 256, 256, 0, stream>>>(aggLb, stats, gamma, beta, out);
}

// Round 16
// 189.770 us; speedup vs baseline: 1.1906x; 1.0138x over previous
//
#include <hip/hip_runtime.h>
#include <cstdint>

#define NN 100000
#define DD 128
#define EE 1000000
#define NBK 782         // buckets of 256 rows over 2*NN combined rows
#define SLOT 3008       // fixed edata slot per bucket (mean 2560, +8.8 sigma)
#define CHUNK 8192      // edges per multisplit block (R14 probe confirmed optimum)
#define BN_EPS 1e-5f

typedef __attribute__((ext_vector_type(4))) float f32x4;
typedef __attribute__((ext_vector_type(8))) short bf16x8;
typedef __attribute__((ext_vector_type(8))) unsigned short u16x8;

__device__ __forceinline__ unsigned short f2bf(float f) {
  union { float f; unsigned u; } c; c.f = f;
  unsigned u = c.u;
  return (unsigned short)((u + 0x7FFFu + ((u >> 16) & 1u)) >> 16);  // RNE
}
__device__ __forceinline__ float bf2f(unsigned short h) {
  union { unsigned u; float f; } c; c.u = ((unsigned)h) << 16;
  return c.f;
}
__device__ __forceinline__ void gld16(const void* g, void* l) {
  __builtin_amdgcn_global_load_lds(
      (const __attribute__((address_space(1))) unsigned int*)g,
      (__attribute__((address_space(3))) unsigned int*)l, 16, 0, 0);
}

// ---------------------------------------------------------------- init: slot cursors + stats zero
__global__ __launch_bounds__(256) void init_k(int* __restrict__ gCur,
                                              float* __restrict__ stats) {
  int g = blockIdx.x * 256 + threadIdx.x;  // 5 blocks = 1280
  if (g < 1024) gCur[g] = g * SLOT;
  else if (g < 1280) stats[g - 1024] = 0.f;
}

// ---------------------------------------------------------------- multisplit scatter + fused xcvt/packB
__global__ __launch_bounds__(256) void bscat_k(const int* __restrict__ lei,
                                               const int* __restrict__ gei,
                                               int* __restrict__ gCur,
                                               unsigned* __restrict__ edata,
                                               const float* __restrict__ x,
                                               char* __restrict__ xbD,
                                               const float* __restrict__ W1,
                                               const float* __restrict__ W2L,
                                               const float* __restrict__ W2G,
                                               unsigned short* __restrict__ Bw) {
  __shared__ int lofs[1025];
  __shared__ int lcur[1024];
  __shared__ int gbase[1024];
  __shared__ unsigned short bid[CHUNK];
  __shared__ unsigned stage[CHUNK];
  __shared__ int wsum[4];
  int t = threadIdx.x;
#pragma unroll
  for (int k = 0; k < 4; ++k) lofs[t * 4 + k] = 0;

  // ---- fused xcvt: x -> bf16 dense [NN][256B]  (grid-stride, hides under LDS phases)
  for (int i8 = blockIdx.x * 256 + t; i8 < NN * DD / 8; i8 += gridDim.x * 256) {
    int row = i8 >> 4, c = i8 & 15;
    const float* src = x + (size_t)row * DD + c * 8;
    f32x4 v0 = *(const f32x4*)src;
    f32x4 v1 = *(const f32x4*)(src + 4);
    u16x8 h;
    h[0] = f2bf(v0[0]); h[1] = f2bf(v0[1]); h[2] = f2bf(v0[2]); h[3] = f2bf(v0[3]);
    h[4] = f2bf(v1[0]); h[5] = f2bf(v1[1]); h[6] = f2bf(v1[2]); h[7] = f2bf(v1[3]);
    *(u16x8*)(xbD + (size_t)row * 256 + c * 16) = h;
  }
  // ---- fused packB: B [128][384] bf16
  for (int g = blockIdx.x * 256 + t; g < DD * 384; g += gridDim.x * 256) {
    int j = g / 384, k = g - j * 384;
    const float* W = (k < DD) ? W1 : ((k < 2 * DD) ? W2L : W2G);
    Bw[g] = f2bf(W[j * DD + (k & (DD - 1))]);
  }

  // ---- original multisplit ----
  int base = blockIdx.x * CHUNK;
  int cnt = 2 * EE - base; if (cnt > CHUNK) cnt = CHUNK;
  __syncthreads();
#pragma unroll 4
  for (int j = 0; j < CHUNK / 256; ++j) {
    int i = base + j * 256 + t;
    if (i < 2 * EE) {
      int grow = (i < EE) ? lei[i] : (NN + gei[i - EE]);
      atomicAdd(&lofs[grow >> 8], 1);
    }
  }
  __syncthreads();
  int v[4];
#pragma unroll
  for (int k = 0; k < 4; ++k) v[k] = lofs[t * 4 + k];
  int tot = v[0] + v[1] + v[2] + v[3];
  int lane = t & 63, wv = t >> 6;
  int inc = tot;
  for (int d = 1; d < 64; d <<= 1) { int u = __shfl_up(inc, d); if (lane >= d) inc += u; }
  if (lane == 63) wsum[wv] = inc;
  __syncthreads();
  int woff = 0;
#pragma unroll
  for (int w = 0; w < 4; ++w) if (w < wv) woff += wsum[w];
  int run = woff + inc - tot;
#pragma unroll
  for (int k = 0; k < 4; ++k) { lofs[t * 4 + k] = run; lcur[t * 4 + k] = run; run += v[k]; }
  if (t == 0) lofs[1024] = cnt;
  __syncthreads();
#pragma unroll 4
  for (int j = 0; j < CHUNK / 256; ++j) {
    int i = base + j * 256 + t;
    if (i < 2 * EE) {
      int grow, col;
      if (i < EE) { grow = lei[i]; col = lei[EE + i]; }
      else        { grow = NN + gei[i - EE]; col = gei[i]; }
      int b = grow >> 8;
      int pos = atomicAdd(&lcur[b], 1);
      stage[pos] = (unsigned)col | ((unsigned)(grow & 255) << 24);
      bid[pos] = (unsigned short)b;
    }
  }
  __syncthreads();
#pragma unroll
  for (int k = 0; k < 4; ++k) {
    int b = t * 4 + k;
    int c = lofs[b + 1] - lofs[b];
    if (c > 0) gbase[b] = atomicAdd(&gCur[b], c);
  }
  __syncthreads();
  for (int i = t; i < cnt; i += 256) {
    int b = bid[i];
    edata[gbase[b] + (i - lofs[b])] = stage[i];
  }
}

// ---------------------------------------------------------------- per-half-bucket LDS CSR + gather
// XCD pair co-location: g -> b=(g>>4)*8+(g&7), half=(g>>3)&1.
// Gather loop unrolled x2 with independent accumulator sets (R16): breaks the
// serial FADD chain so 2 row-loads are in flight per lane.
__global__ __launch_bounds__(256) void bgather_k(const char* __restrict__ xbD,
                                                 const int* __restrict__ gCur,
                                                 const unsigned* __restrict__ edata,
                                                 unsigned short* __restrict__ aggLb,
                                                 char* __restrict__ outD) {
  __shared__ int rowOff[129];
  __shared__ int rowCur[128];
  __shared__ unsigned colS[2048];
  __shared__ int wsum1;
  int t = threadIdx.x;
  int g = blockIdx.x;
  int b = (g >> 4) * 8 + (g & 7);
  int half = (g >> 3) & 1;
  if (b >= NBK) return;
  int s0 = b * SLOT;
  int cnt = gCur[b] - s0;
  if (t < 128) rowCur[t] = 0;
  __syncthreads();
  for (int i = t; i < cnt; i += 256) {
    unsigned e = edata[s0 + i];
    unsigned r8 = e >> 24;
    if ((int)(r8 >> 7) == half) atomicAdd(&rowCur[r8 & 127], 1);
  }
  __syncthreads();
  int v = 0, inc = 0;
  if (t < 128) {
    v = rowCur[t];
    inc = v;
    int lane = t & 63;
    for (int d = 1; d < 64; d <<= 1) { int u = __shfl_up(inc, d); if (lane >= d) inc += u; }
    if (t == 63) wsum1 = inc;
  }
  __syncthreads();
  if (t < 128) {
    int excl = inc - v + ((t >> 6) ? wsum1 : 0);
    rowOff[t] = excl;
    if (t == 127) rowOff[128] = excl + v;
    rowCur[t] = excl;
  }
  __syncthreads();
  for (int i = t; i < cnt; i += 256) {
    unsigned e = edata[s0 + i];
    unsigned r8 = e >> 24;
    if ((int)(r8 >> 7) == half) {
      int pos = atomicAdd(&rowCur[r8 & 127], 1);
      if (pos < 2048) colS[pos] = e & 0xFFFFFFu;
    }
  }
  __syncthreads();
  int g16 = t >> 4, lane16 = t & 15;
  int rowsbase = b * 256 + half * 128;
  for (int r = g16; r < 128; r += 16) {
    int grow = rowsbase + r;
    if (grow >= 2 * NN) break;
    int e0 = rowOff[r], e1 = rowOff[r + 1];
    float a0[8] = {0.f, 0.f, 0.f, 0.f, 0.f, 0.f, 0.f, 0.f};
    float a1[8] = {0.f, 0.f, 0.f, 0.f, 0.f, 0.f, 0.f, 0.f};
    int i = e0;
    for (; i + 1 < e1; i += 2) {
      unsigned c0 = colS[i], c1 = colS[i + 1];
      u16x8 v0 = *(const u16x8*)(xbD + (size_t)c0 * 256 + lane16 * 16);
      u16x8 v1 = *(const u16x8*)(xbD + (size_t)c1 * 256 + lane16 * 16);
#pragma unroll
      for (int j = 0; j < 8; ++j) { a0[j] += bf2f(v0[j]); a1[j] += bf2f(v1[j]); }
    }
    if (i < e1) {
      unsigned c0 = colS[i];
      u16x8 v0 = *(const u16x8*)(xbD + (size_t)c0 * 256 + lane16 * 16);
#pragma unroll
      for (int j = 0; j < 8; ++j) a0[j] += bf2f(v0[j]);
    }
    u16x8 hv;
#pragma unroll
    for (int j = 0; j < 8; ++j) hv[j] = f2bf(a0[j] + a1[j]);
    if (grow < NN)
      *(u16x8*)(aggLb + (size_t)grow * DD + lane16 * 8) = hv;
    else
      *(u16x8*)(outD + (size_t)(grow - NN) * 512 + 256 + lane16 * 16) = hv;
  }
}

// ---------------------------------------------------------------- GEMM BK=32, 4 blocks/CU, bf16 C over aggLb
__global__ __launch_bounds__(256, 4) void gemm_k(
    const char* __restrict__ xbD, unsigned short* __restrict__ aggLb,
    const char* __restrict__ outD, const unsigned short* __restrict__ Bw,
    float* __restrict__ stats) {
  __shared__ unsigned short Asm[2][128 * 32];  // 8KB each
  __shared__ unsigned short Bsm[2][128 * 32];
  __shared__ float red[4][256];
  int t = threadIdx.x, wave = t >> 6, lane = t & 63;
  int row0 = blockIdx.x * 128;

  f32x4 acc[2][8];
#pragma unroll
  for (int mi = 0; mi < 2; ++mi)
#pragma unroll
    for (int ni = 0; ni < 8; ++ni) acc[mi][ni] = (f32x4){0.f, 0.f, 0.f, 0.f};

  // rows are 64B (4 chunks of 16B); swizzle chunk c -> c ^ ((r>>1)&3).
  // LDS dest linear: 16B per thread slot -> short index (i*256+wave*64)*8.
  auto STAGE = [&](int s, int b) {
#pragma unroll
    for (int i = 0; i < 2; ++i) {
      int flat = t + i * 256, r = flat >> 2, c = flat & 3;
      int cs = c ^ ((r >> 1) & 3);
      int rr = row0 + r; rr = (rr < NN) ? rr : (NN - 1);
      const char* src;
      if (s < 4)      src = xbD + (size_t)rr * 256 + (s & 3) * 64 + cs * 16;
      else if (s < 8) src = (const char*)aggLb + (size_t)rr * 256 + (s - 4) * 64 + cs * 16;
      else            src = outD + (size_t)rr * 512 + 256 + (s - 8) * 64 + cs * 16;
      gld16(src, &Asm[b][(size_t)(i * 256 + wave * 64) * 8]);
    }
#pragma unroll
    for (int i = 0; i < 2; ++i) {
      int flat = t + i * 256, n = flat >> 2, c = flat & 3;
      int cs = c ^ ((n >> 1) & 3);
      const char* src = (const char*)Bw + (size_t)n * 768 + s * 64 + cs * 16;
      gld16(src, &Bsm[b][(size_t)(i * 256 + wave * 64) * 8]);
    }
  };

  auto COMPUTE = [&](int b) {
    int mr = lane & 15, kq = lane >> 4;
    int r0 = wave * 32 + mr, r1 = r0 + 16;
    bf16x8 a0 = *(const bf16x8*)&Asm[b][((size_t)r0 * 4 + (kq ^ ((r0 >> 1) & 3))) * 8];
    bf16x8 a1 = *(const bf16x8*)&Asm[b][((size_t)r1 * 4 + (kq ^ ((r1 >> 1) & 3))) * 8];
#pragma unroll
    for (int ni = 0; ni < 8; ++ni) {
      int nr = ni * 16 + mr;
      bf16x8 bb = *(const bf16x8*)&Bsm[b][((size_t)nr * 4 + (kq ^ ((nr >> 1) & 3))) * 8];
      acc[0][ni] = __builtin_amdgcn_mfma_f32_16x16x32_bf16(a0, bb, acc[0][ni], 0, 0, 0);
      acc[1][ni] = __builtin_amdgcn_mfma_f32_16x16x32_bf16(a1, bb, acc[1][ni], 0, 0, 0);
    }
  };

  STAGE(0, 0);
  __syncthreads();
#pragma unroll
  for (int s = 0; s < 12; ++s) {
    int b = s & 1;
    if (s < 11) STAGE(s + 1, b ^ 1);
    COMPUTE(b);
    __syncthreads();
  }

  // epilogue: C/D layout col=lane&15, row=(lane>>4)*4+reg; C -> bf16 over aggLb (own rows)
  int colbase = lane & 15, rbase = (lane >> 4) * 4;
#pragma unroll
  for (int ni = 0; ni < 8; ++ni) {
    int col = ni * 16 + colbase;
    float s = 0.f, q = 0.f;
#pragma unroll
    for (int mi = 0; mi < 2; ++mi)
#pragma unroll
      for (int r = 0; r < 4; ++r) {
        int row = row0 + wave * 32 + mi * 16 + rbase + r;
        float v = acc[mi][ni][r];
        if (row < NN) {
          aggLb[(size_t)row * DD + col] = f2bf(v);
          s += v; q += v * v;
        }
      }
    s += __shfl_xor(s, 16); s += __shfl_xor(s, 32);
    q += __shfl_xor(q, 16); q += __shfl_xor(q, 32);
    if (lane < 16) { red[wave][col] = s; red[wave][128 + col] = q; }
  }
  __syncthreads();
  float v = red[0][t & 255] + red[1][t & 255] + red[2][t & 255] + red[3][t & 255];
  atomicAdd(&stats[t & 255], v);
}

// ---------------------------------------------------------------- BN finalize + apply + ReLU (fused)
__global__ __launch_bounds__(256) void bn_relu_k(const unsigned short* __restrict__ Cb,
                                                 const float* __restrict__ stats,
                                                 const float* __restrict__ gamma,
                                                 const float* __restrict__ beta,
                                                 float* __restrict__ out) {
  __shared__ float sc[128], sh[128];
  int t = threadIdx.x;
  if (t < 128) {
    float mean = stats[t] * (1.f / NN);
    float var = stats[DD + t] * (1.f / NN) - mean * mean;
    float inv = rsqrtf(var + BN_EPS);
    float s = gamma[t] * inv;
    sc[t] = s;
    sh[t] = beta[t] - mean * s;
  }
  __syncthreads();
  int i8 = blockIdx.x * 256 + t;  // 1.6M exact
  int row = i8 >> 4, c = i8 & 15;
  u16x8 h = *(const u16x8*)(Cb + (size_t)row * DD + c * 8);
  int f0 = c * 8;
  f32x4 o0, o1;
#pragma unroll
  for (int j = 0; j < 4; ++j) {
    o0[j] = fmaxf(bf2f(h[j]) * sc[f0 + j] + sh[f0 + j], 0.f);
    o1[j] = fmaxf(bf2f(h[4 + j]) * sc[f0 + 4 + j] + sh[f0 + 4 + j], 0.f);
  }
  float* dst = out + (size_t)row * DD + f0;
  *(f32x4*)dst = o0;
  *(f32x4*)(dst + 4) = o1;
}

// ---------------------------------------------------------------- launch
extern "C" void kernel_launch(void* const* d_in, const int* in_sizes, int n_in,
                              void* d_out, int out_size, void* d_ws, size_t ws_size,
                              hipStream_t stream) {
  const float* x     = (const float*)d_in[0];
  const int*   lei   = (const int*)d_in[1];
  const int*   gei   = (const int*)d_in[2];
  const float* W1    = (const float*)d_in[3];
  const float* W2L   = (const float*)d_in[4];
  const float* W2G   = (const float*)d_in[5];
  const float* gamma = (const float*)d_in[6];
  const float* beta  = (const float*)d_in[7];
  float* out = (float*)d_out;
  char* outD = (char*)d_out;  // aggG lives in odd 256B halves of out rows

  char* w = (char*)d_ws;
  size_t o = 0;
  char* xbD = (char*)(w + o); o += (size_t)NN * 256;                           // 25.6MB dense bf16 x
  unsigned short* aggLb = (unsigned short*)(w + o); o += (size_t)NN * DD * 2;  // 25.6MB (later holds bf16 C)
  unsigned* edata = (unsigned*)(w + o); o += (size_t)NBK * SLOT * 4;           // 9.41MB
  int* gCur = (int*)(w + o); o += 1024 * 4;
  unsigned short* Bw = (unsigned short*)(w + o); o += (size_t)DD * 384 * 2;    // 96KB
  float* stats = (float*)(w + o); o += 1024;   // total ~60.71MB

  init_k<<<5, 256, 0, stream>>>(gCur, stats);

  int nbc = (2 * EE + CHUNK - 1) / CHUNK;  // 245
  bscat_k<<<nbc, 256, 0, stream>>>(lei, gei, gCur, edata, x, xbD, W1, W2L, W2G, Bw);
  bgather_k<<<1568, 256, 0, stream>>>(xbD, gCur, edata, aggLb, outD);

  gemm_k<<<(NN + 127) / 128, 256, 0, stream>>>(xbD, aggLb, outD, Bw, stats);
  bn_relu_k<<<(NN * DD / 8) / 256, 256, 0, stream>>>(aggLb, stats, gamma, beta, out);
}

// Round 17
// 173.753 us; speedup vs baseline: 1.3004x; 1.0922x over previous
//
#include <hip/hip_runtime.h>
#include <cstdint>

#define NN 100000
#define DD 128
#define EE 1000000
#define NBK 782         // buckets of 256 rows over 2*NN combined rows
#define SLOT 3008       // fixed edata slot per bucket (mean 2560, +8.8 sigma)
#define CHUNK 8192      // edges per multisplit block (R14 probe confirmed optimum)
#define BN_EPS 1e-5f

typedef __attribute__((ext_vector_type(4))) float f32x4;
typedef __attribute__((ext_vector_type(8))) short bf16x8;
typedef __attribute__((ext_vector_type(8))) unsigned short u16x8;

__device__ __forceinline__ unsigned short f2bf(float f) {
  union { float f; unsigned u; } c; c.f = f;
  unsigned u = c.u;
  return (unsigned short)((u + 0x7FFFu + ((u >> 16) & 1u)) >> 16);  // RNE
}
__device__ __forceinline__ float bf2f(unsigned short h) {
  union { unsigned u; float f; } c; c.u = ((unsigned)h) << 16;
  return c.f;
}
__device__ __forceinline__ void gld16(const void* g, void* l) {
  __builtin_amdgcn_global_load_lds(
      (const __attribute__((address_space(1))) unsigned int*)g,
      (__attribute__((address_space(3))) unsigned int*)l, 16, 0, 0);
}

// ---------------------------------------------------------------- init: slot cursors + stats zero
__global__ __launch_bounds__(256) void init_k(int* __restrict__ gCur,
                                              float* __restrict__ stats) {
  int g = blockIdx.x * 256 + threadIdx.x;  // 5 blocks = 1280
  if (g < 1024) gCur[g] = g * SLOT;
  else if (g < 1280) stats[g - 1024] = 0.f;
}

// ---------------------------------------------------------------- multisplit scatter + fused xcvt/packB
// R17: 512 threads/block (halves per-block serial trip counts; CHUNK and
// bucket-run lengths unchanged -> flush coalescing preserved).
__global__ __launch_bounds__(512) void bscat_k(const int* __restrict__ lei,
                                               const int* __restrict__ gei,
                                               int* __restrict__ gCur,
                                               unsigned* __restrict__ edata,
                                               const float* __restrict__ x,
                                               char* __restrict__ xbD,
                                               const float* __restrict__ W1,
                                               const float* __restrict__ W2L,
                                               const float* __restrict__ W2G,
                                               unsigned short* __restrict__ Bw) {
  __shared__ int lofs[1025];
  __shared__ int lcur[1024];
  __shared__ int gbase[1024];
  __shared__ unsigned short bid[CHUNK];
  __shared__ unsigned stage[CHUNK];
  __shared__ int wsum[8];
  int t = threadIdx.x;
#pragma unroll
  for (int k = 0; k < 2; ++k) lofs[t * 2 + k] = 0;

  // ---- fused xcvt: x -> bf16 dense [NN][256B]  (grid-stride)
  for (int i8 = blockIdx.x * 512 + t; i8 < NN * DD / 8; i8 += gridDim.x * 512) {
    int row = i8 >> 4, c = i8 & 15;
    const float* src = x + (size_t)row * DD + c * 8;
    f32x4 v0 = *(const f32x4*)src;
    f32x4 v1 = *(const f32x4*)(src + 4);
    u16x8 h;
    h[0] = f2bf(v0[0]); h[1] = f2bf(v0[1]); h[2] = f2bf(v0[2]); h[3] = f2bf(v0[3]);
    h[4] = f2bf(v1[0]); h[5] = f2bf(v1[1]); h[6] = f2bf(v1[2]); h[7] = f2bf(v1[3]);
    *(u16x8*)(xbD + (size_t)row * 256 + c * 16) = h;
  }
  // ---- fused packB: B [128][384] bf16
  for (int g = blockIdx.x * 512 + t; g < DD * 384; g += gridDim.x * 512) {
    int j = g / 384, k = g - j * 384;
    const float* W = (k < DD) ? W1 : ((k < 2 * DD) ? W2L : W2G);
    Bw[g] = f2bf(W[j * DD + (k & (DD - 1))]);
  }

  // ---- multisplit ----
  int base = blockIdx.x * CHUNK;
  int cnt = 2 * EE - base; if (cnt > CHUNK) cnt = CHUNK;
  __syncthreads();
#pragma unroll 4
  for (int j = 0; j < CHUNK / 512; ++j) {   // 16 trips
    int i = base + j * 512 + t;
    if (i < 2 * EE) {
      int grow = (i < EE) ? lei[i] : (NN + gei[i - EE]);
      atomicAdd(&lofs[grow >> 8], 1);
    }
  }
  __syncthreads();
  int v[2];
#pragma unroll
  for (int k = 0; k < 2; ++k) v[k] = lofs[t * 2 + k];
  int tot = v[0] + v[1];
  int lane = t & 63, wv = t >> 6;           // 8 waves
  int inc = tot;
  for (int d = 1; d < 64; d <<= 1) { int u = __shfl_up(inc, d); if (lane >= d) inc += u; }
  if (lane == 63) wsum[wv] = inc;
  __syncthreads();
  int woff = 0;
#pragma unroll
  for (int w = 0; w < 8; ++w) if (w < wv) woff += wsum[w];
  int run = woff + inc - tot;
#pragma unroll
  for (int k = 0; k < 2; ++k) { lofs[t * 2 + k] = run; lcur[t * 2 + k] = run; run += v[k]; }
  if (t == 0) lofs[1024] = cnt;
  __syncthreads();
#pragma unroll 4
  for (int j = 0; j < CHUNK / 512; ++j) {
    int i = base + j * 512 + t;
    if (i < 2 * EE) {
      int grow, col;
      if (i < EE) { grow = lei[i]; col = lei[EE + i]; }
      else        { grow = NN + gei[i - EE]; col = gei[i]; }
      int b = grow >> 8;
      int pos = atomicAdd(&lcur[b], 1);
      stage[pos] = (unsigned)col | ((unsigned)(grow & 255) << 24);
      bid[pos] = (unsigned short)b;
    }
  }
  __syncthreads();
#pragma unroll
  for (int k = 0; k < 2; ++k) {
    int b = t * 2 + k;
    int c = lofs[b + 1] - lofs[b];
    if (c > 0) gbase[b] = atomicAdd(&gCur[b], c);
  }
  __syncthreads();
  for (int i = t; i < cnt; i += 512) {
    int b = bid[i];
    edata[gbase[b] + (i - lofs[b])] = stage[i];
  }
}

// ---------------------------------------------------------------- per-half-bucket LDS CSR + gather (R16 version)
// XCD pair co-location: g -> b=(g>>4)*8+(g&7), half=(g>>3)&1.
// Gather loop unrolled x2 with independent accumulator sets.
__global__ __launch_bounds__(256) void bgather_k(const char* __restrict__ xbD,
                                                 const int* __restrict__ gCur,
                                                 const unsigned* __restrict__ edata,
                                                 unsigned short* __restrict__ aggLb,
                                                 char* __restrict__ outD) {
  __shared__ int rowOff[129];
  __shared__ int rowCur[128];
  __shared__ unsigned colS[2048];
  __shared__ int wsum1;
  int t = threadIdx.x;
  int g = blockIdx.x;
  int b = (g >> 4) * 8 + (g & 7);
  int half = (g >> 3) & 1;
  if (b >= NBK) return;
  int s0 = b * SLOT;
  int cnt = gCur[b] - s0;
  if (t < 128) rowCur[t] = 0;
  __syncthreads();
  for (int i = t; i < cnt; i += 256) {
    unsigned e = edata[s0 + i];
    unsigned r8 = e >> 24;
    if ((int)(r8 >> 7) == half) atomicAdd(&rowCur[r8 & 127], 1);
  }
  __syncthreads();
  int v = 0, inc = 0;
  if (t < 128) {
    v = rowCur[t];
    inc = v;
    int lane = t & 63;
    for (int d = 1; d < 64; d <<= 1) { int u = __shfl_up(inc, d); if (lane >= d) inc += u; }
    if (t == 63) wsum1 = inc;
  }
  __syncthreads();
  if (t < 128) {
    int excl = inc - v + ((t >> 6) ? wsum1 : 0);
    rowOff[t] = excl;
    if (t == 127) rowOff[128] = excl + v;
    rowCur[t] = excl;
  }
  __syncthreads();
  for (int i = t; i < cnt; i += 256) {
    unsigned e = edata[s0 + i];
    unsigned r8 = e >> 24;
    if ((int)(r8 >> 7) == half) {
      int pos = atomicAdd(&rowCur[r8 & 127], 1);
      if (pos < 2048) colS[pos] = e & 0xFFFFFFu;
    }
  }
  __syncthreads();
  int g16 = t >> 4, lane16 = t & 15;
  int rowsbase = b * 256 + half * 128;
  for (int r = g16; r < 128; r += 16) {
    int grow = rowsbase + r;
    if (grow >= 2 * NN) break;
    int e0 = rowOff[r], e1 = rowOff[r + 1];
    float a0[8] = {0.f, 0.f, 0.f, 0.f, 0.f, 0.f, 0.f, 0.f};
    float a1[8] = {0.f, 0.f, 0.f, 0.f, 0.f, 0.f, 0.f, 0.f};
    int i = e0;
    for (; i + 1 < e1; i += 2) {
      unsigned c0 = colS[i], c1 = colS[i + 1];
      u16x8 v0 = *(const u16x8*)(xbD + (size_t)c0 * 256 + lane16 * 16);
      u16x8 v1 = *(const u16x8*)(xbD + (size_t)c1 * 256 + lane16 * 16);
#pragma unroll
      for (int j = 0; j < 8; ++j) { a0[j] += bf2f(v0[j]); a1[j] += bf2f(v1[j]); }
    }
    if (i < e1) {
      unsigned c0 = colS[i];
      u16x8 v0 = *(const u16x8*)(xbD + (size_t)c0 * 256 + lane16 * 16);
#pragma unroll
      for (int j = 0; j < 8; ++j) a0[j] += bf2f(v0[j]);
    }
    u16x8 hv;
#pragma unroll
    for (int j = 0; j < 8; ++j) hv[j] = f2bf(a0[j] + a1[j]);
    if (grow < NN)
      *(u16x8*)(aggLb + (size_t)grow * DD + lane16 * 8) = hv;
    else
      *(u16x8*)(outD + (size_t)(grow - NN) * 512 + 256 + lane16 * 16) = hv;
  }
}

// ---------------------------------------------------------------- GEMM BK=32, 4 blocks/CU, bf16 C over aggLb
__global__ __launch_bounds__(256, 4) void gemm_k(
    const char* __restrict__ xbD, unsigned short* __restrict__ aggLb,
    const char* __restrict__ outD, const unsigned short* __restrict__ Bw,
    float* __restrict__ stats) {
  __shared__ unsigned short Asm[2][128 * 32];  // 8KB each
  __shared__ unsigned short Bsm[2][128 * 32];
  __shared__ float red[4][256];
  int t = threadIdx.x, wave = t >> 6, lane = t & 63;
  int row0 = blockIdx.x * 128;

  f32x4 acc[2][8];
#pragma unroll
  for (int mi = 0; mi < 2; ++mi)
#pragma unroll
    for (int ni = 0; ni < 8; ++ni) acc[mi][ni] = (f32x4){0.f, 0.f, 0.f, 0.f};

  // rows are 64B (4 chunks of 16B); swizzle chunk c -> c ^ ((r>>1)&3).
  // LDS dest linear: 16B per thread slot -> short index (i*256+wave*64)*8.
  auto STAGE = [&](int s, int b) {
#pragma unroll
    for (int i = 0; i < 2; ++i) {
      int flat = t + i * 256, r = flat >> 2, c = flat & 3;
      int cs = c ^ ((r >> 1) & 3);
      int rr = row0 + r; rr = (rr < NN) ? rr : (NN - 1);
      const char* src;
      if (s < 4)      src = xbD + (size_t)rr * 256 + (s & 3) * 64 + cs * 16;
      else if (s < 8) src = (const char*)aggLb + (size_t)rr * 256 + (s - 4) * 64 + cs * 16;
      else            src = outD + (size_t)rr * 512 + 256 + (s - 8) * 64 + cs * 16;
      gld16(src, &Asm[b][(size_t)(i * 256 + wave * 64) * 8]);
    }
#pragma unroll
    for (int i = 0; i < 2; ++i) {
      int flat = t + i * 256, n = flat >> 2, c = flat & 3;
      int cs = c ^ ((n >> 1) & 3);
      const char* src = (const char*)Bw + (size_t)n * 768 + s * 64 + cs * 16;
      gld16(src, &Bsm[b][(size_t)(i * 256 + wave * 64) * 8]);
    }
  };

  auto COMPUTE = [&](int b) {
    int mr = lane & 15, kq = lane >> 4;
    int r0 = wave * 32 + mr, r1 = r0 + 16;
    bf16x8 a0 = *(const bf16x8*)&Asm[b][((size_t)r0 * 4 + (kq ^ ((r0 >> 1) & 3))) * 8];
    bf16x8 a1 = *(const bf16x8*)&Asm[b][((size_t)r1 * 4 + (kq ^ ((r1 >> 1) & 3))) * 8];
#pragma unroll
    for (int ni = 0; ni < 8; ++ni) {
      int nr = ni * 16 + mr;
      bf16x8 bb = *(const bf16x8*)&Bsm[b][((size_t)nr * 4 + (kq ^ ((nr >> 1) & 3))) * 8];
      acc[0][ni] = __builtin_amdgcn_mfma_f32_16x16x32_bf16(a0, bb, acc[0][ni], 0, 0, 0);
      acc[1][ni] = __builtin_amdgcn_mfma_f32_16x16x32_bf16(a1, bb, acc[1][ni], 0, 0, 0);
    }
  };

  STAGE(0, 0);
  __syncthreads();
#pragma unroll
  for (int s = 0; s < 12; ++s) {
    int b = s & 1;
    if (s < 11) STAGE(s + 1, b ^ 1);
    COMPUTE(b);
    __syncthreads();
  }

  // epilogue: C/D layout col=lane&15, row=(lane>>4)*4+reg; C -> bf16 over aggLb (own rows)
  int colbase = lane & 15, rbase = (lane >> 4) * 4;
#pragma unroll
  for (int ni = 0; ni < 8; ++ni) {
    int col = ni * 16 + colbase;
    float s = 0.f, q = 0.f;
#pragma unroll
    for (int mi = 0; mi < 2; ++mi)
#pragma unroll
      for (int r = 0; r < 4; ++r) {
        int row = row0 + wave * 32 + mi * 16 + rbase + r;
        float v = acc[mi][ni][r];
        if (row < NN) {
          aggLb[(size_t)row * DD + col] = f2bf(v);
          s += v; q += v * v;
        }
      }
    s += __shfl_xor(s, 16); s += __shfl_xor(s, 32);
    q += __shfl_xor(q, 16); q += __shfl_xor(q, 32);
    if (lane < 16) { red[wave][col] = s; red[wave][128 + col] = q; }
  }
  __syncthreads();
  float v = red[0][t & 255] + red[1][t & 255] + red[2][t & 255] + red[3][t & 255];
  atomicAdd(&stats[t & 255], v);
}

// ---------------------------------------------------------------- BN finalize + apply + ReLU (fused)
__global__ __launch_bounds__(256) void bn_relu_k(const unsigned short* __restrict__ Cb,
                                                 const float* __restrict__ stats,
                                                 const float* __restrict__ gamma,
                                                 const float* __restrict__ beta,
                                                 float* __restrict__ out) {
  __shared__ float sc[128], sh[128];
  int t = threadIdx.x;
  if (t < 128) {
    float mean = stats[t] * (1.f / NN);
    float var = stats[DD + t] * (1.f / NN) - mean * mean;
    float inv = rsqrtf(var + BN_EPS);
    float s = gamma[t] * inv;
    sc[t] = s;
    sh[t] = beta[t] - mean * s;
  }
  __syncthreads();
  int i8 = blockIdx.x * 256 + t;  // 1.6M exact
  int row = i8 >> 4, c = i8 & 15;
  u16x8 h = *(const u16x8*)(Cb + (size_t)row * DD + c * 8);
  int f0 = c * 8;
  f32x4 o0, o1;
#pragma unroll
  for (int j = 0; j < 4; ++j) {
    o0[j] = fmaxf(bf2f(h[j]) * sc[f0 + j] + sh[f0 + j], 0.f);
    o1[j] = fmaxf(bf2f(h[4 + j]) * sc[f0 + 4 + j] + sh[f0 + 4 + j], 0.f);
  }
  float* dst = out + (size_t)row * DD + f0;
  *(f32x4*)dst = o0;
  *(f32x4*)(dst + 4) = o1;
}

// ---------------------------------------------------------------- launch
extern "C" void kernel_launch(void* const* d_in, const int* in_sizes, int n_in,
                              void* d_out, int out_size, void* d_ws, size_t ws_size,
                              hipStream_t stream) {
  const float* x     = (const float*)d_in[0];
  const int*   lei   = (const int*)d_in[1];
  const int*   gei   = (const int*)d_in[2];
  const float* W1    = (const float*)d_in[3];
  const float* W2L   = (const float*)d_in[4];
  const float* W2G   = (const float*)d_in[5];
  const float* gamma = (const float*)d_in[6];
  const float* beta  = (const float*)d_in[7];
  float* out = (float*)d_out;
  char* outD = (char*)d_out;  // aggG lives in odd 256B halves of out rows

  char* w = (char*)d_ws;
  size_t o = 0;
  char* xbD = (char*)(w + o); o += (size_t)NN * 256;                           // 25.6MB dense bf16 x
  unsigned short* aggLb = (unsigned short*)(w + o); o += (size_t)NN * DD * 2;  // 25.6MB (later holds bf16 C)
  unsigned* edata = (unsigned*)(w + o); o += (size_t)NBK * SLOT * 4;           // 9.41MB
  int* gCur = (int*)(w + o); o += 1024 * 4;
  unsigned short* Bw = (unsigned short*)(w + o); o += (size_t)DD * 384 * 2;    // 96KB
  float* stats = (float*)(w + o); o += 1024;   // total ~60.71MB

  init_k<<<5, 256, 0, stream>>>(gCur, stats);

  int nbc = (2 * EE + CHUNK - 1) / CHUNK;  // 245
  bscat_k<<<nbc, 512, 0, stream>>>(lei, gei, gCur, edata, x, xbD, W1, W2L, W2G, Bw);
  bgather_k<<<1568, 256, 0, stream>>>(xbD, gCur, edata, aggLb, outD);

  gemm_k<<<(NN + 127) / 128, 256, 0, stream>>>(xbD, aggLb, outD, Bw, stats);
  bn_relu_k<<<(NN * DD / 8) / 256, 256, 0, stream>>>(aggLb, stats, gamma, beta, out);
}

// Round 18
// 166.169 us; speedup vs baseline: 1.3598x; 1.0456x over previous
//
#include <hip/hip_runtime.h>
#include <cstdint>

#define NN 100000
#define DD 128
#define EE 1000000
#define NBK 782         // buckets of 256 rows over 2*NN combined rows
#define SLOT 3008       // fixed edata slot per bucket (mean 2560, +8.8 sigma)
#define CHUNK 8192      // edges per multisplit block (R14 probe confirmed optimum)
#define BN_EPS 1e-5f

typedef __attribute__((ext_vector_type(4))) float f32x4;
typedef __attribute__((ext_vector_type(8))) short bf16x8;
typedef __attribute__((ext_vector_type(8))) unsigned short u16x8;

__device__ __forceinline__ unsigned short f2bf(float f) {
  union { float f; unsigned u; } c; c.f = f;
  unsigned u = c.u;
  return (unsigned short)((u + 0x7FFFu + ((u >> 16) & 1u)) >> 16);  // RNE
}
__device__ __forceinline__ float bf2f(unsigned short h) {
  union { unsigned u; float f; } c; c.u = ((unsigned)h) << 16;
  return c.f;
}
__device__ __forceinline__ void gld16(const void* g, void* l) {
  __builtin_amdgcn_global_load_lds(
      (const __attribute__((address_space(1))) unsigned int*)g,
      (__attribute__((address_space(3))) unsigned int*)l, 16, 0, 0);
}

// ---------------------------------------------------------------- init: slot cursors + stats zero
__global__ __launch_bounds__(256) void init_k(int* __restrict__ gCur,
                                              float* __restrict__ stats) {
  int g = blockIdx.x * 256 + threadIdx.x;  // 5 blocks = 1280
  if (g < 1024) gCur[g] = g * SLOT;
  else if (g < 1280) stats[g - 1024] = 0.f;
}

// ---------------------------------------------------------------- multisplit scatter + fused xcvt/packB
// R18: 1024 threads/block (halves per-block serial trip counts vs R17's 512;
// CHUNK and bucket-run lengths unchanged -> flush coalescing preserved).
__global__ __launch_bounds__(1024) void bscat_k(const int* __restrict__ lei,
                                                const int* __restrict__ gei,
                                                int* __restrict__ gCur,
                                                unsigned* __restrict__ edata,
                                                const float* __restrict__ x,
                                                char* __restrict__ xbD,
                                                const float* __restrict__ W1,
                                                const float* __restrict__ W2L,
                                                const float* __restrict__ W2G,
                                                unsigned short* __restrict__ Bw) {
  __shared__ int lofs[1025];
  __shared__ int lcur[1024];
  __shared__ int gbase[1024];
  __shared__ unsigned short bid[CHUNK];
  __shared__ unsigned stage[CHUNK];
  __shared__ int wsum[16];
  int t = threadIdx.x;
  lofs[t] = 0;

  // ---- fused xcvt: x -> bf16 dense [NN][256B]  (grid-stride)
  for (int i8 = blockIdx.x * 1024 + t; i8 < NN * DD / 8; i8 += gridDim.x * 1024) {
    int row = i8 >> 4, c = i8 & 15;
    const float* src = x + (size_t)row * DD + c * 8;
    f32x4 v0 = *(const f32x4*)src;
    f32x4 v1 = *(const f32x4*)(src + 4);
    u16x8 h;
    h[0] = f2bf(v0[0]); h[1] = f2bf(v0[1]); h[2] = f2bf(v0[2]); h[3] = f2bf(v0[3]);
    h[4] = f2bf(v1[0]); h[5] = f2bf(v1[1]); h[6] = f2bf(v1[2]); h[7] = f2bf(v1[3]);
    *(u16x8*)(xbD + (size_t)row * 256 + c * 16) = h;
  }
  // ---- fused packB: B [128][384] bf16
  for (int g = blockIdx.x * 1024 + t; g < DD * 384; g += gridDim.x * 1024) {
    int j = g / 384, k = g - j * 384;
    const float* W = (k < DD) ? W1 : ((k < 2 * DD) ? W2L : W2G);
    Bw[g] = f2bf(W[j * DD + (k & (DD - 1))]);
  }

  // ---- multisplit ----
  int base = blockIdx.x * CHUNK;
  int cnt = 2 * EE - base; if (cnt > CHUNK) cnt = CHUNK;
  __syncthreads();
#pragma unroll 4
  for (int j = 0; j < CHUNK / 1024; ++j) {  // 8 trips
    int i = base + j * 1024 + t;
    if (i < 2 * EE) {
      int grow = (i < EE) ? lei[i] : (NN + gei[i - EE]);
      atomicAdd(&lofs[grow >> 8], 1);
    }
  }
  __syncthreads();
  // scan: each thread owns exactly 1 bucket; 16-wave two-level scan
  int v = lofs[t];
  int lane = t & 63, wv = t >> 6;           // 16 waves
  int inc = v;
  for (int d = 1; d < 64; d <<= 1) { int u = __shfl_up(inc, d); if (lane >= d) inc += u; }
  if (lane == 63) wsum[wv] = inc;
  __syncthreads();
  int woff = 0;
#pragma unroll
  for (int w = 0; w < 16; ++w) if (w < wv) woff += wsum[w];
  int run = woff + inc - v;                 // exclusive prefix for bucket t
  lofs[t] = run;
  lcur[t] = run;
  if (t == 0) lofs[1024] = cnt;
  __syncthreads();
#pragma unroll 4
  for (int j = 0; j < CHUNK / 1024; ++j) {
    int i = base + j * 1024 + t;
    if (i < 2 * EE) {
      int grow, col;
      if (i < EE) { grow = lei[i]; col = lei[EE + i]; }
      else        { grow = NN + gei[i - EE]; col = gei[i]; }
      int b = grow >> 8;
      int pos = atomicAdd(&lcur[b], 1);
      stage[pos] = (unsigned)col | ((unsigned)(grow & 255) << 24);
      bid[pos] = (unsigned short)b;
    }
  }
  __syncthreads();
  {
    int c = lofs[t + 1] - lofs[t];
    if (c > 0) gbase[t] = atomicAdd(&gCur[t], c);
  }
  __syncthreads();
  for (int i = t; i < cnt; i += 1024) {
    int b = bid[i];
    edata[gbase[b] + (i - lofs[b])] = stage[i];
  }
}

// ---------------------------------------------------------------- per-half-bucket LDS CSR + gather (R16 version)
// XCD pair co-location: g -> b=(g>>4)*8+(g&7), half=(g>>3)&1.
// Gather loop unrolled x2 with independent accumulator sets.
__global__ __launch_bounds__(256) void bgather_k(const char* __restrict__ xbD,
                                                 const int* __restrict__ gCur,
                                                 const unsigned* __restrict__ edata,
                                                 unsigned short* __restrict__ aggLb,
                                                 char* __restrict__ outD) {
  __shared__ int rowOff[129];
  __shared__ int rowCur[128];
  __shared__ unsigned colS[2048];
  __shared__ int wsum1;
  int t = threadIdx.x;
  int g = blockIdx.x;
  int b = (g >> 4) * 8 + (g & 7);
  int half = (g >> 3) & 1;
  if (b >= NBK) return;
  int s0 = b * SLOT;
  int cnt = gCur[b] - s0;
  if (t < 128) rowCur[t] = 0;
  __syncthreads();
  for (int i = t; i < cnt; i += 256) {
    unsigned e = edata[s0 + i];
    unsigned r8 = e >> 24;
    if ((int)(r8 >> 7) == half) atomicAdd(&rowCur[r8 & 127], 1);
  }
  __syncthreads();
  int v = 0, inc = 0;
  if (t < 128) {
    v = rowCur[t];
    inc = v;
    int lane = t & 63;
    for (int d = 1; d < 64; d <<= 1) { int u = __shfl_up(inc, d); if (lane >= d) inc += u; }
    if (t == 63) wsum1 = inc;
  }
  __syncthreads();
  if (t < 128) {
    int excl = inc - v + ((t >> 6) ? wsum1 : 0);
    rowOff[t] = excl;
    if (t == 127) rowOff[128] = excl + v;
    rowCur[t] = excl;
  }
  __syncthreads();
  for (int i = t; i < cnt; i += 256) {
    unsigned e = edata[s0 + i];
    unsigned r8 = e >> 24;
    if ((int)(r8 >> 7) == half) {
      int pos = atomicAdd(&rowCur[r8 & 127], 1);
      if (pos < 2048) colS[pos] = e & 0xFFFFFFu;
    }
  }
  __syncthreads();
  int g16 = t >> 4, lane16 = t & 15;
  int rowsbase = b * 256 + half * 128;
  for (int r = g16; r < 128; r += 16) {
    int grow = rowsbase + r;
    if (grow >= 2 * NN) break;
    int e0 = rowOff[r], e1 = rowOff[r + 1];
    float a0[8] = {0.f, 0.f, 0.f, 0.f, 0.f, 0.f, 0.f, 0.f};
    float a1[8] = {0.f, 0.f, 0.f, 0.f, 0.f, 0.f, 0.f, 0.f};
    int i = e0;
    for (; i + 1 < e1; i += 2) {
      unsigned c0 = colS[i], c1 = colS[i + 1];
      u16x8 v0 = *(const u16x8*)(xbD + (size_t)c0 * 256 + lane16 * 16);
      u16x8 v1 = *(const u16x8*)(xbD + (size_t)c1 * 256 + lane16 * 16);
#pragma unroll
      for (int j = 0; j < 8; ++j) { a0[j] += bf2f(v0[j]); a1[j] += bf2f(v1[j]); }
    }
    if (i < e1) {
      unsigned c0 = colS[i];
      u16x8 v0 = *(const u16x8*)(xbD + (size_t)c0 * 256 + lane16 * 16);
#pragma unroll
      for (int j = 0; j < 8; ++j) a0[j] += bf2f(v0[j]);
    }
    u16x8 hv;
#pragma unroll
    for (int j = 0; j < 8; ++j) hv[j] = f2bf(a0[j] + a1[j]);
    if (grow < NN)
      *(u16x8*)(aggLb + (size_t)grow * DD + lane16 * 8) = hv;
    else
      *(u16x8*)(outD + (size_t)(grow - NN) * 512 + 256 + lane16 * 16) = hv;
  }
}

// ---------------------------------------------------------------- GEMM BK=32, 4 blocks/CU, bf16 C over aggLb
__global__ __launch_bounds__(256, 4) void gemm_k(
    const char* __restrict__ xbD, unsigned short* __restrict__ aggLb,
    const char* __restrict__ outD, const unsigned short* __restrict__ Bw,
    float* __restrict__ stats) {
  __shared__ unsigned short Asm[2][128 * 32];  // 8KB each
  __shared__ unsigned short Bsm[2][128 * 32];
  __shared__ float red[4][256];
  int t = threadIdx.x, wave = t >> 6, lane = t & 63;
  int row0 = blockIdx.x * 128;

  f32x4 acc[2][8];
#pragma unroll
  for (int mi = 0; mi < 2; ++mi)
#pragma unroll
    for (int ni = 0; ni < 8; ++ni) acc[mi][ni] = (f32x4){0.f, 0.f, 0.f, 0.f};

  // rows are 64B (4 chunks of 16B); swizzle chunk c -> c ^ ((r>>1)&3).
  // LDS dest linear: 16B per thread slot -> short index (i*256+wave*64)*8.
  auto STAGE = [&](int s, int b) {
#pragma unroll
    for (int i = 0; i < 2; ++i) {
      int flat = t + i * 256, r = flat >> 2, c = flat & 3;
      int cs = c ^ ((r >> 1) & 3);
      int rr = row0 + r; rr = (rr < NN) ? rr : (NN - 1);
      const char* src;
      if (s < 4)      src = xbD + (size_t)rr * 256 + (s & 3) * 64 + cs * 16;
      else if (s < 8) src = (const char*)aggLb + (size_t)rr * 256 + (s - 4) * 64 + cs * 16;
      else            src = outD + (size_t)rr * 512 + 256 + (s - 8) * 64 + cs * 16;
      gld16(src, &Asm[b][(size_t)(i * 256 + wave * 64) * 8]);
    }
#pragma unroll
    for (int i = 0; i < 2; ++i) {
      int flat = t + i * 256, n = flat >> 2, c = flat & 3;
      int cs = c ^ ((n >> 1) & 3);
      const char* src = (const char*)Bw + (size_t)n * 768 + s * 64 + cs * 16;
      gld16(src, &Bsm[b][(size_t)(i * 256 + wave * 64) * 8]);
    }
  };

  auto COMPUTE = [&](int b) {
    int mr = lane & 15, kq = lane >> 4;
    int r0 = wave * 32 + mr, r1 = r0 + 16;
    bf16x8 a0 = *(const bf16x8*)&Asm[b][((size_t)r0 * 4 + (kq ^ ((r0 >> 1) & 3))) * 8];
    bf16x8 a1 = *(const bf16x8*)&Asm[b][((size_t)r1 * 4 + (kq ^ ((r1 >> 1) & 3))) * 8];
#pragma unroll
    for (int ni = 0; ni < 8; ++ni) {
      int nr = ni * 16 + mr;
      bf16x8 bb = *(const bf16x8*)&Bsm[b][((size_t)nr * 4 + (kq ^ ((nr >> 1) & 3))) * 8];
      acc[0][ni] = __builtin_amdgcn_mfma_f32_16x16x32_bf16(a0, bb, acc[0][ni], 0, 0, 0);
      acc[1][ni] = __builtin_amdgcn_mfma_f32_16x16x32_bf16(a1, bb, acc[1][ni], 0, 0, 0);
    }
  };

  STAGE(0, 0);
  __syncthreads();
#pragma unroll
  for (int s = 0; s < 12; ++s) {
    int b = s & 1;
    if (s < 11) STAGE(s + 1, b ^ 1);
    COMPUTE(b);
    __syncthreads();
  }

  // epilogue: C/D layout col=lane&15, row=(lane>>4)*4+reg; C -> bf16 over aggLb (own rows)
  int colbase = lane & 15, rbase = (lane >> 4) * 4;
#pragma unroll
  for (int ni = 0; ni < 8; ++ni) {
    int col = ni * 16 + colbase;
    float s = 0.f, q = 0.f;
#pragma unroll
    for (int mi = 0; mi < 2; ++mi)
#pragma unroll
      for (int r = 0; r < 4; ++r) {
        int row = row0 + wave * 32 + mi * 16 + rbase + r;
        float v = acc[mi][ni][r];
        if (row < NN) {
          aggLb[(size_t)row * DD + col] = f2bf(v);
          s += v; q += v * v;
        }
      }
    s += __shfl_xor(s, 16); s += __shfl_xor(s, 32);
    q += __shfl_xor(q, 16); q += __shfl_xor(q, 32);
    if (lane < 16) { red[wave][col] = s; red[wave][128 + col] = q; }
  }
  __syncthreads();
  float v = red[0][t & 255] + red[1][t & 255] + red[2][t & 255] + red[3][t & 255];
  atomicAdd(&stats[t & 255], v);
}

// ---------------------------------------------------------------- BN finalize + apply + ReLU (fused)
__global__ __launch_bounds__(256) void bn_relu_k(const unsigned short* __restrict__ Cb,
                                                 const float* __restrict__ stats,
                                                 const float* __restrict__ gamma,
                                                 const float* __restrict__ beta,
                                                 float* __restrict__ out) {
  __shared__ float sc[128], sh[128];
  int t = threadIdx.x;
  if (t < 128) {
    float mean = stats[t] * (1.f / NN);
    float var = stats[DD + t] * (1.f / NN) - mean * mean;
    float inv = rsqrtf(var + BN_EPS);
    float s = gamma[t] * inv;
    sc[t] = s;
    sh[t] = beta[t] - mean * s;
  }
  __syncthreads();
  int i8 = blockIdx.x * 256 + t;  // 1.6M exact
  int row = i8 >> 4, c = i8 & 15;
  u16x8 h = *(const u16x8*)(Cb + (size_t)row * DD + c * 8);
  int f0 = c * 8;
  f32x4 o0, o1;
#pragma unroll
  for (int j = 0; j < 4; ++j) {
    o0[j] = fmaxf(bf2f(h[j]) * sc[f0 + j] + sh[f0 + j], 0.f);
    o1[j] = fmaxf(bf2f(h[4 + j]) * sc[f0 + 4 + j] + sh[f0 + 4 + j], 0.f);
  }
  float* dst = out + (size_t)row * DD + f0;
  *(f32x4*)dst = o0;
  *(f32x4*)(dst + 4) = o1;
}

// ---------------------------------------------------------------- launch
extern "C" void kernel_launch(void* const* d_in, const int* in_sizes, int n_in,
                              void* d_out, int out_size, void* d_ws, size_t ws_size,
                              hipStream_t stream) {
  const float* x     = (const float*)d_in[0];
  const int*   lei   = (const int*)d_in[1];
  const int*   gei   = (const int*)d_in[2];
  const float* W1    = (const float*)d_in[3];
  const float* W2L   = (const float*)d_in[4];
  const float* W2G   = (const float*)d_in[5];
  const float* gamma = (const float*)d_in[6];
  const float* beta  = (const float*)d_in[7];
  float* out = (float*)d_out;
  char* outD = (char*)d_out;  // aggG lives in odd 256B halves of out rows

  char* w = (char*)d_ws;
  size_t o = 0;
  char* xbD = (char*)(w + o); o += (size_t)NN * 256;                           // 25.6MB dense bf16 x
  unsigned short* aggLb = (unsigned short*)(w + o); o += (size_t)NN * DD * 2;  // 25.6MB (later holds bf16 C)
  unsigned* edata = (unsigned*)(w + o); o += (size_t)NBK * SLOT * 4;           // 9.41MB
  int* gCur = (int*)(w + o); o += 1024 * 4;
  unsigned short* Bw = (unsigned short*)(w + o); o += (size_t)DD * 384 * 2;    // 96KB
  float* stats = (float*)(w + o); o += 1024;   // total ~60.71MB

  init_k<<<5, 256, 0, stream>>>(gCur, stats);

  int nbc = (2 * EE + CHUNK - 1) / CHUNK;  // 245
  bscat_k<<<nbc, 1024, 0, stream>>>(lei, gei, gCur, edata, x, xbD, W1, W2L, W2G, Bw);
  bgather_k<<<1568, 256, 0, stream>>>(xbD, gCur, edata, aggLb, outD);

  gemm_k<<<(NN + 127) / 128, 256, 0, stream>>>(xbD, aggLb, outD, Bw, stats);
  bn_relu_k<<<(NN * DD / 8) / 256, 256, 0, stream>>>(aggLb, stats, gamma, beta, out);
}

// Round 19
// 162.348 us; speedup vs baseline: 1.3918x; 1.0235x over previous
//
#include <hip/hip_runtime.h>
#include <cstdint>

#define NN 100000
#define DD 128
#define EE 1000000
#define NBK 782         // buckets of 256 rows over 2*NN combined rows
#define SLOT 3008       // fixed edata slot per bucket (mean 2560, +8.8 sigma)
#define CHUNK 8192      // edges per multisplit block (R14 probe confirmed optimum)
#define BN_EPS 1e-5f

typedef __attribute__((ext_vector_type(4))) float f32x4;
typedef __attribute__((ext_vector_type(4))) int i32x4;
typedef __attribute__((ext_vector_type(8))) short bf16x8;
typedef __attribute__((ext_vector_type(8))) unsigned short u16x8;

__device__ __forceinline__ unsigned short f2bf(float f) {
  union { float f; unsigned u; } c; c.f = f;
  unsigned u = c.u;
  return (unsigned short)((u + 0x7FFFu + ((u >> 16) & 1u)) >> 16);  // RNE
}
__device__ __forceinline__ float bf2f(unsigned short h) {
  union { unsigned u; float f; } c; c.u = ((unsigned)h) << 16;
  return c.f;
}
__device__ __forceinline__ void gld16(const void* g, void* l) {
  __builtin_amdgcn_global_load_lds(
      (const __attribute__((address_space(1))) unsigned int*)g,
      (__attribute__((address_space(3))) unsigned int*)l, 16, 0, 0);
}

// ---------------------------------------------------------------- init: slot cursors + stats zero
__global__ __launch_bounds__(256) void init_k(int* __restrict__ gCur,
                                              float* __restrict__ stats) {
  int g = blockIdx.x * 256 + threadIdx.x;  // 5 blocks = 1280
  if (g < 1024) gCur[g] = g * SLOT;
  else if (g < 1280) stats[g - 1024] = 0.f;
}

// ---------------------------------------------------------------- multisplit scatter + fused xcvt/packB
// R19: int4 edge loads (EE%4==0 -> quads never straddle the lei/gei boundary);
// hist and scatter passes drop from 8 serial trips to 2 each.
__global__ __launch_bounds__(1024) void bscat_k(const int* __restrict__ lei,
                                                const int* __restrict__ gei,
                                                int* __restrict__ gCur,
                                                unsigned* __restrict__ edata,
                                                const float* __restrict__ x,
                                                char* __restrict__ xbD,
                                                const float* __restrict__ W1,
                                                const float* __restrict__ W2L,
                                                const float* __restrict__ W2G,
                                                unsigned short* __restrict__ Bw) {
  __shared__ int lofs[1025];
  __shared__ int lcur[1024];
  __shared__ int gbase[1024];
  __shared__ unsigned short bid[CHUNK];
  __shared__ unsigned stage[CHUNK];
  __shared__ int wsum[16];
  int t = threadIdx.x;
  lofs[t] = 0;

  // ---- fused xcvt: x -> bf16 dense [NN][256B]  (grid-stride)
  for (int i8 = blockIdx.x * 1024 + t; i8 < NN * DD / 8; i8 += gridDim.x * 1024) {
    int row = i8 >> 4, c = i8 & 15;
    const float* src = x + (size_t)row * DD + c * 8;
    f32x4 v0 = *(const f32x4*)src;
    f32x4 v1 = *(const f32x4*)(src + 4);
    u16x8 h;
    h[0] = f2bf(v0[0]); h[1] = f2bf(v0[1]); h[2] = f2bf(v0[2]); h[3] = f2bf(v0[3]);
    h[4] = f2bf(v1[0]); h[5] = f2bf(v1[1]); h[6] = f2bf(v1[2]); h[7] = f2bf(v1[3]);
    *(u16x8*)(xbD + (size_t)row * 256 + c * 16) = h;
  }
  // ---- fused packB: B [128][384] bf16
  for (int g = blockIdx.x * 1024 + t; g < DD * 384; g += gridDim.x * 1024) {
    int j = g / 384, k = g - j * 384;
    const float* W = (k < DD) ? W1 : ((k < 2 * DD) ? W2L : W2G);
    Bw[g] = f2bf(W[j * DD + (k & (DD - 1))]);
  }

  // ---- multisplit ----
  int base = blockIdx.x * CHUNK;
  int cnt = 2 * EE - base; if (cnt > CHUNK) cnt = CHUNK;
  __syncthreads();
  // hist: 2 trips of int4 (4 edges/thread)
#pragma unroll
  for (int j = 0; j < CHUNK / 4096; ++j) {
    int i4 = base + j * 4096 + t * 4;
    if (i4 < 2 * EE) {
      i32x4 rows = (i4 < EE) ? *(const i32x4*)(lei + i4)
                             : *(const i32x4*)(gei + (i4 - EE));
      int add = (i4 < EE) ? 0 : NN;
#pragma unroll
      for (int k = 0; k < 4; ++k) atomicAdd(&lofs[(rows[k] + add) >> 8], 1);
    }
  }
  __syncthreads();
  // scan: each thread owns exactly 1 bucket; 16-wave two-level scan
  int v = lofs[t];
  int lane = t & 63, wv = t >> 6;           // 16 waves
  int inc = v;
  for (int d = 1; d < 64; d <<= 1) { int u = __shfl_up(inc, d); if (lane >= d) inc += u; }
  if (lane == 63) wsum[wv] = inc;
  __syncthreads();
  int woff = 0;
#pragma unroll
  for (int w = 0; w < 16; ++w) if (w < wv) woff += wsum[w];
  int run = woff + inc - v;                 // exclusive prefix for bucket t
  lofs[t] = run;
  lcur[t] = run;
  if (t == 0) lofs[1024] = cnt;
  __syncthreads();
  // scatter: 2 trips of int4 rows + int4 cols
#pragma unroll
  for (int j = 0; j < CHUNK / 4096; ++j) {
    int i4 = base + j * 4096 + t * 4;
    if (i4 < 2 * EE) {
      i32x4 rows, cols;
      int add;
      if (i4 < EE) {
        rows = *(const i32x4*)(lei + i4);
        cols = *(const i32x4*)(lei + EE + i4);
        add = 0;
      } else {
        rows = *(const i32x4*)(gei + (i4 - EE));
        cols = *(const i32x4*)(gei + i4);     // = gei[EE + (i4-EE)]
        add = NN;
      }
#pragma unroll
      for (int k = 0; k < 4; ++k) {
        int grow = rows[k] + add;
        int b = grow >> 8;
        int pos = atomicAdd(&lcur[b], 1);
        stage[pos] = (unsigned)cols[k] | ((unsigned)(grow & 255) << 24);
        bid[pos] = (unsigned short)b;
      }
    }
  }
  __syncthreads();
  {
    int c = lofs[t + 1] - lofs[t];
    if (c > 0) gbase[t] = atomicAdd(&gCur[t], c);
  }
  __syncthreads();
  for (int i = t; i < cnt; i += 1024) {
    int b = bid[i];
    edata[gbase[b] + (i - lofs[b])] = stage[i];
  }
}

// ---------------------------------------------------------------- per-half-bucket LDS CSR + gather (R16 version)
// XCD pair co-location: g -> b=(g>>4)*8+(g&7), half=(g>>3)&1.
// Gather loop unrolled x2 with independent accumulator sets.
__global__ __launch_bounds__(256) void bgather_k(const char* __restrict__ xbD,
                                                 const int* __restrict__ gCur,
                                                 const unsigned* __restrict__ edata,
                                                 unsigned short* __restrict__ aggLb,
                                                 char* __restrict__ outD) {
  __shared__ int rowOff[129];
  __shared__ int rowCur[128];
  __shared__ unsigned colS[2048];
  __shared__ int wsum1;
  int t = threadIdx.x;
  int g = blockIdx.x;
  int b = (g >> 4) * 8 + (g & 7);
  int half = (g >> 3) & 1;
  if (b >= NBK) return;
  int s0 = b * SLOT;
  int cnt = gCur[b] - s0;
  if (t < 128) rowCur[t] = 0;
  __syncthreads();
  for (int i = t; i < cnt; i += 256) {
    unsigned e = edata[s0 + i];
    unsigned r8 = e >> 24;
    if ((int)(r8 >> 7) == half) atomicAdd(&rowCur[r8 & 127], 1);
  }
  __syncthreads();
  int v = 0, inc = 0;
  if (t < 128) {
    v = rowCur[t];
    inc = v;
    int lane = t & 63;
    for (int d = 1; d < 64; d <<= 1) { int u = __shfl_up(inc, d); if (lane >= d) inc += u; }
    if (t == 63) wsum1 = inc;
  }
  __syncthreads();
  if (t < 128) {
    int excl = inc - v + ((t >> 6) ? wsum1 : 0);
    rowOff[t] = excl;
    if (t == 127) rowOff[128] = excl + v;
    rowCur[t] = excl;
  }
  __syncthreads();
  for (int i = t; i < cnt; i += 256) {
    unsigned e = edata[s0 + i];
    unsigned r8 = e >> 24;
    if ((int)(r8 >> 7) == half) {
      int pos = atomicAdd(&rowCur[r8 & 127], 1);
      if (pos < 2048) colS[pos] = e & 0xFFFFFFu;
    }
  }
  __syncthreads();
  int g16 = t >> 4, lane16 = t & 15;
  int rowsbase = b * 256 + half * 128;
  for (int r = g16; r < 128; r += 16) {
    int grow = rowsbase + r;
    if (grow >= 2 * NN) break;
    int e0 = rowOff[r], e1 = rowOff[r + 1];
    float a0[8] = {0.f, 0.f, 0.f, 0.f, 0.f, 0.f, 0.f, 0.f};
    float a1[8] = {0.f, 0.f, 0.f, 0.f, 0.f, 0.f, 0.f, 0.f};
    int i = e0;
    for (; i + 1 < e1; i += 2) {
      unsigned c0 = colS[i], c1 = colS[i + 1];
      u16x8 v0 = *(const u16x8*)(xbD + (size_t)c0 * 256 + lane16 * 16);
      u16x8 v1 = *(const u16x8*)(xbD + (size_t)c1 * 256 + lane16 * 16);
#pragma unroll
      for (int j = 0; j < 8; ++j) { a0[j] += bf2f(v0[j]); a1[j] += bf2f(v1[j]); }
    }
    if (i < e1) {
      unsigned c0 = colS[i];
      u16x8 v0 = *(const u16x8*)(xbD + (size_t)c0 * 256 + lane16 * 16);
#pragma unroll
      for (int j = 0; j < 8; ++j) a0[j] += bf2f(v0[j]);
    }
    u16x8 hv;
#pragma unroll
    for (int j = 0; j < 8; ++j) hv[j] = f2bf(a0[j] + a1[j]);
    if (grow < NN)
      *(u16x8*)(aggLb + (size_t)grow * DD + lane16 * 8) = hv;
    else
      *(u16x8*)(outD + (size_t)(grow - NN) * 512 + 256 + lane16 * 16) = hv;
  }
}

// ---------------------------------------------------------------- GEMM BK=32, 4 blocks/CU, bf16 C over aggLb
__global__ __launch_bounds__(256, 4) void gemm_k(
    const char* __restrict__ xbD, unsigned short* __restrict__ aggLb,
    const char* __restrict__ outD, const unsigned short* __restrict__ Bw,
    float* __restrict__ stats) {
  __shared__ unsigned short Asm[2][128 * 32];  // 8KB each
  __shared__ unsigned short Bsm[2][128 * 32];
  __shared__ float red[4][256];
  int t = threadIdx.x, wave = t >> 6, lane = t & 63;
  int row0 = blockIdx.x * 128;

  f32x4 acc[2][8];
#pragma unroll
  for (int mi = 0; mi < 2; ++mi)
#pragma unroll
    for (int ni = 0; ni < 8; ++ni) acc[mi][ni] = (f32x4){0.f, 0.f, 0.f, 0.f};

  // rows are 64B (4 chunks of 16B); swizzle chunk c -> c ^ ((r>>1)&3).
  // LDS dest linear: 16B per thread slot -> short index (i*256+wave*64)*8.
  auto STAGE = [&](int s, int b) {
#pragma unroll
    for (int i = 0; i < 2; ++i) {
      int flat = t + i * 256, r = flat >> 2, c = flat & 3;
      int cs = c ^ ((r >> 1) & 3);
      int rr = row0 + r; rr = (rr < NN) ? rr : (NN - 1);
      const char* src;
      if (s < 4)      src = xbD + (size_t)rr * 256 + (s & 3) * 64 + cs * 16;
      else if (s < 8) src = (const char*)aggLb + (size_t)rr * 256 + (s - 4) * 64 + cs * 16;
      else            src = outD + (size_t)rr * 512 + 256 + (s - 8) * 64 + cs * 16;
      gld16(src, &Asm[b][(size_t)(i * 256 + wave * 64) * 8]);
    }
#pragma unroll
    for (int i = 0; i < 2; ++i) {
      int flat = t + i * 256, n = flat >> 2, c = flat & 3;
      int cs = c ^ ((n >> 1) & 3);
      const char* src = (const char*)Bw + (size_t)n * 768 + s * 64 + cs * 16;
      gld16(src, &Bsm[b][(size_t)(i * 256 + wave * 64) * 8]);
    }
  };

  auto COMPUTE = [&](int b) {
    int mr = lane & 15, kq = lane >> 4;
    int r0 = wave * 32 + mr, r1 = r0 + 16;
    bf16x8 a0 = *(const bf16x8*)&Asm[b][((size_t)r0 * 4 + (kq ^ ((r0 >> 1) & 3))) * 8];
    bf16x8 a1 = *(const bf16x8*)&Asm[b][((size_t)r1 * 4 + (kq ^ ((r1 >> 1) & 3))) * 8];
#pragma unroll
    for (int ni = 0; ni < 8; ++ni) {
      int nr = ni * 16 + mr;
      bf16x8 bb = *(const bf16x8*)&Bsm[b][((size_t)nr * 4 + (kq ^ ((nr >> 1) & 3))) * 8];
      acc[0][ni] = __builtin_amdgcn_mfma_f32_16x16x32_bf16(a0, bb, acc[0][ni], 0, 0, 0);
      acc[1][ni] = __builtin_amdgcn_mfma_f32_16x16x32_bf16(a1, bb, acc[1][ni], 0, 0, 0);
    }
  };

  STAGE(0, 0);
  __syncthreads();
#pragma unroll
  for (int s = 0; s < 12; ++s) {
    int b = s & 1;
    if (s < 11) STAGE(s + 1, b ^ 1);
    COMPUTE(b);
    __syncthreads();
  }

  // epilogue: C/D layout col=lane&15, row=(lane>>4)*4+reg; C -> bf16 over aggLb (own rows)
  int colbase = lane & 15, rbase = (lane >> 4) * 4;
#pragma unroll
  for (int ni = 0; ni < 8; ++ni) {
    int col = ni * 16 + colbase;
    float s = 0.f, q = 0.f;
#pragma unroll
    for (int mi = 0; mi < 2; ++mi)
#pragma unroll
      for (int r = 0; r < 4; ++r) {
        int row = row0 + wave * 32 + mi * 16 + rbase + r;
        float v = acc[mi][ni][r];
        if (row < NN) {
          aggLb[(size_t)row * DD + col] = f2bf(v);
          s += v; q += v * v;
        }
      }
    s += __shfl_xor(s, 16); s += __shfl_xor(s, 32);
    q += __shfl_xor(q, 16); q += __shfl_xor(q, 32);
    if (lane < 16) { red[wave][col] = s; red[wave][128 + col] = q; }
  }
  __syncthreads();
  float v = red[0][t & 255] + red[1][t & 255] + red[2][t & 255] + red[3][t & 255];
  atomicAdd(&stats[t & 255], v);
}

// ---------------------------------------------------------------- BN finalize + apply + ReLU (fused)
__global__ __launch_bounds__(256) void bn_relu_k(const unsigned short* __restrict__ Cb,
                                                 const float* __restrict__ stats,
                                                 const float* __restrict__ gamma,
                                                 const float* __restrict__ beta,
                                                 float* __restrict__ out) {
  __shared__ float sc[128], sh[128];
  int t = threadIdx.x;
  if (t < 128) {
    float mean = stats[t] * (1.f / NN);
    float var = stats[DD + t] * (1.f / NN) - mean * mean;
    float inv = rsqrtf(var + BN_EPS);
    float s = gamma[t] * inv;
    sc[t] = s;
    sh[t] = beta[t] - mean * s;
  }
  __syncthreads();
  int i8 = blockIdx.x * 256 + t;  // 1.6M exact
  int row = i8 >> 4, c = i8 & 15;
  u16x8 h = *(const u16x8*)(Cb + (size_t)row * DD + c * 8);
  int f0 = c * 8;
  f32x4 o0, o1;
#pragma unroll
  for (int j = 0; j < 4; ++j) {
    o0[j] = fmaxf(bf2f(h[j]) * sc[f0 + j] + sh[f0 + j], 0.f);
    o1[j] = fmaxf(bf2f(h[4 + j]) * sc[f0 + 4 + j] + sh[f0 + 4 + j], 0.f);
  }
  float* dst = out + (size_t)row * DD + f0;
  *(f32x4*)dst = o0;
  *(f32x4*)(dst + 4) = o1;
}

// ---------------------------------------------------------------- launch
extern "C" void kernel_launch(void* const* d_in, const int* in_sizes, int n_in,
                              void* d_out, int out_size, void* d_ws, size_t ws_size,
                              hipStream_t stream) {
  const float* x     = (const float*)d_in[0];
  const int*   lei   = (const int*)d_in[1];
  const int*   gei   = (const int*)d_in[2];
  const float* W1    = (const float*)d_in[3];
  const float* W2L   = (const float*)d_in[4];
  const float* W2G   = (const float*)d_in[5];
  const float* gamma = (const float*)d_in[6];
  const float* beta  = (const float*)d_in[7];
  float* out = (float*)d_out;
  char* outD = (char*)d_out;  // aggG lives in odd 256B halves of out rows

  char* w = (char*)d_ws;
  size_t o = 0;
  char* xbD = (char*)(w + o); o += (size_t)NN * 256;                           // 25.6MB dense bf16 x
  unsigned short* aggLb = (unsigned short*)(w + o); o += (size_t)NN * DD * 2;  // 25.6MB (later holds bf16 C)
  unsigned* edata = (unsigned*)(w + o); o += (size_t)NBK * SLOT * 4;           // 9.41MB
  int* gCur = (int*)(w + o); o += 1024 * 4;
  unsigned short* Bw = (unsigned short*)(w + o); o += (size_t)DD * 384 * 2;    // 96KB
  float* stats = (float*)(w + o); o += 1024;   // total ~60.71MB

  init_k<<<5, 256, 0, stream>>>(gCur, stats);

  int nbc = (2 * EE + CHUNK - 1) / CHUNK;  // 245
  bscat_k<<<nbc, 1024, 0, stream>>>(lei, gei, gCur, edata, x, xbD, W1, W2L, W2G, Bw);
  bgather_k<<<1568, 256, 0, stream>>>(xbD, gCur, edata, aggLb, outD);

  gemm_k<<<(NN + 127) / 128, 256, 0, stream>>>(xbD, aggLb, outD, Bw, stats);
  bn_relu_k<<<(NN * DD / 8) / 256, 256, 0, stream>>>(aggLb, stats, gamma, beta, out);
}

// Round 20
// 150.630 us; speedup vs baseline: 1.5000x; 1.0778x over previous
//
#include <hip/hip_runtime.h>
#include <cstdint>

#define NN 100000
#define DD 128
#define EE 1000000
#define NBK 782         // buckets of 256 rows over 2*NN combined rows
#define SLOT 3008       // fixed edata slot per bucket (mean 2560, +8.8 sigma)
#define CHUNK 8192      // edges per multisplit block (R14 probe confirmed optimum)
#define BN_EPS 1e-5f

typedef __attribute__((ext_vector_type(4))) float f32x4;
typedef __attribute__((ext_vector_type(4))) int i32x4;
typedef __attribute__((ext_vector_type(8))) short bf16x8;
typedef __attribute__((ext_vector_type(8))) unsigned short u16x8;

__device__ __forceinline__ unsigned short f2bf(float f) {
  union { float f; unsigned u; } c; c.f = f;
  unsigned u = c.u;
  return (unsigned short)((u + 0x7FFFu + ((u >> 16) & 1u)) >> 16);  // RNE
}
__device__ __forceinline__ float bf2f(unsigned short h) {
  union { unsigned u; float f; } c; c.u = ((unsigned)h) << 16;
  return c.f;
}
__device__ __forceinline__ void gld16(const void* g, void* l) {
  __builtin_amdgcn_global_load_lds(
      (const __attribute__((address_space(1))) unsigned int*)g,
      (__attribute__((address_space(3))) unsigned int*)l, 16, 0, 0);
}

// ---------------------------------------------------------------- init: slot cursors + stats zero
__global__ __launch_bounds__(256) void init_k(int* __restrict__ gCur,
                                              float* __restrict__ stats) {
  int g = blockIdx.x * 256 + threadIdx.x;  // 5 blocks = 1280
  if (g < 1024) gCur[g] = g * SLOT;
  else if (g < 1280) stats[g - 1024] = 0.f;
}

// ---------------------------------------------------------------- multisplit scatter + fused xcvt/packB
// int4 edge loads (EE%4==0 -> quads never straddle the lei/gei boundary).
__global__ __launch_bounds__(1024) void bscat_k(const int* __restrict__ lei,
                                                const int* __restrict__ gei,
                                                int* __restrict__ gCur,
                                                unsigned* __restrict__ edata,
                                                const float* __restrict__ x,
                                                char* __restrict__ xbD,
                                                const float* __restrict__ W1,
                                                const float* __restrict__ W2L,
                                                const float* __restrict__ W2G,
                                                unsigned short* __restrict__ Bw) {
  __shared__ int lofs[1025];
  __shared__ int lcur[1024];
  __shared__ int gbase[1024];
  __shared__ unsigned short bid[CHUNK];
  __shared__ unsigned stage[CHUNK];
  __shared__ int wsum[16];
  int t = threadIdx.x;
  lofs[t] = 0;

  // ---- fused xcvt: x -> bf16 dense [NN][256B]  (grid-stride)
  for (int i8 = blockIdx.x * 1024 + t; i8 < NN * DD / 8; i8 += gridDim.x * 1024) {
    int row = i8 >> 4, c = i8 & 15;
    const float* src = x + (size_t)row * DD + c * 8;
    f32x4 v0 = *(const f32x4*)src;
    f32x4 v1 = *(const f32x4*)(src + 4);
    u16x8 h;
    h[0] = f2bf(v0[0]); h[1] = f2bf(v0[1]); h[2] = f2bf(v0[2]); h[3] = f2bf(v0[3]);
    h[4] = f2bf(v1[0]); h[5] = f2bf(v1[1]); h[6] = f2bf(v1[2]); h[7] = f2bf(v1[3]);
    *(u16x8*)(xbD + (size_t)row * 256 + c * 16) = h;
  }
  // ---- fused packB: B [128][384] bf16
  for (int g = blockIdx.x * 1024 + t; g < DD * 384; g += gridDim.x * 1024) {
    int j = g / 384, k = g - j * 384;
    const float* W = (k < DD) ? W1 : ((k < 2 * DD) ? W2L : W2G);
    Bw[g] = f2bf(W[j * DD + (k & (DD - 1))]);
  }

  // ---- multisplit ----
  int base = blockIdx.x * CHUNK;
  int cnt = 2 * EE - base; if (cnt > CHUNK) cnt = CHUNK;
  __syncthreads();
  // hist: 2 trips of int4 (4 edges/thread)
#pragma unroll
  for (int j = 0; j < CHUNK / 4096; ++j) {
    int i4 = base + j * 4096 + t * 4;
    if (i4 < 2 * EE) {
      i32x4 rows = (i4 < EE) ? *(const i32x4*)(lei + i4)
                             : *(const i32x4*)(gei + (i4 - EE));
      int add = (i4 < EE) ? 0 : NN;
#pragma unroll
      for (int k = 0; k < 4; ++k) atomicAdd(&lofs[(rows[k] + add) >> 8], 1);
    }
  }
  __syncthreads();
  // scan: each thread owns exactly 1 bucket; 16-wave two-level scan
  int v = lofs[t];
  int lane = t & 63, wv = t >> 6;           // 16 waves
  int inc = v;
  for (int d = 1; d < 64; d <<= 1) { int u = __shfl_up(inc, d); if (lane >= d) inc += u; }
  if (lane == 63) wsum[wv] = inc;
  __syncthreads();
  int woff = 0;
#pragma unroll
  for (int w = 0; w < 16; ++w) if (w < wv) woff += wsum[w];
  int run = woff + inc - v;                 // exclusive prefix for bucket t
  lofs[t] = run;
  lcur[t] = run;
  if (t == 0) lofs[1024] = cnt;
  __syncthreads();
  // scatter: 2 trips of int4 rows + int4 cols
#pragma unroll
  for (int j = 0; j < CHUNK / 4096; ++j) {
    int i4 = base + j * 4096 + t * 4;
    if (i4 < 2 * EE) {
      i32x4 rows, cols;
      int add;
      if (i4 < EE) {
        rows = *(const i32x4*)(lei + i4);
        cols = *(const i32x4*)(lei + EE + i4);
        add = 0;
      } else {
        rows = *(const i32x4*)(gei + (i4 - EE));
        cols = *(const i32x4*)(gei + i4);
        add = NN;
      }
#pragma unroll
      for (int k = 0; k < 4; ++k) {
        int grow = rows[k] + add;
        int b = grow >> 8;
        int pos = atomicAdd(&lcur[b], 1);
        stage[pos] = (unsigned)cols[k] | ((unsigned)(grow & 255) << 24);
        bid[pos] = (unsigned short)b;
      }
    }
  }
  __syncthreads();
  {
    int c = lofs[t + 1] - lofs[t];
    if (c > 0) gbase[t] = atomicAdd(&gCur[t], c);
  }
  __syncthreads();
  for (int i = t; i < cnt; i += 1024) {
    int b = bid[i];
    edata[gbase[b] + (i - lofs[b])] = stage[i];
  }
}

// ---------------------------------------------------------------- per-half-bucket LDS CSR + gather (R16 version)
// XCD pair co-location: g -> b=(g>>4)*8+(g&7), half=(g>>3)&1.
// Gather loop unrolled x2 with independent accumulator sets.
__global__ __launch_bounds__(256) void bgather_k(const char* __restrict__ xbD,
                                                 const int* __restrict__ gCur,
                                                 const unsigned* __restrict__ edata,
                                                 unsigned short* __restrict__ aggLb,
                                                 char* __restrict__ outD) {
  __shared__ int rowOff[129];
  __shared__ int rowCur[128];
  __shared__ unsigned colS[2048];
  __shared__ int wsum1;
  int t = threadIdx.x;
  int g = blockIdx.x;
  int b = (g >> 4) * 8 + (g & 7);
  int half = (g >> 3) & 1;
  if (b >= NBK) return;
  int s0 = b * SLOT;
  int cnt = gCur[b] - s0;
  if (t < 128) rowCur[t] = 0;
  __syncthreads();
  for (int i = t; i < cnt; i += 256) {
    unsigned e = edata[s0 + i];
    unsigned r8 = e >> 24;
    if ((int)(r8 >> 7) == half) atomicAdd(&rowCur[r8 & 127], 1);
  }
  __syncthreads();
  int v = 0, inc = 0;
  if (t < 128) {
    v = rowCur[t];
    inc = v;
    int lane = t & 63;
    for (int d = 1; d < 64; d <<= 1) { int u = __shfl_up(inc, d); if (lane >= d) inc += u; }
    if (t == 63) wsum1 = inc;
  }
  __syncthreads();
  if (t < 128) {
    int excl = inc - v + ((t >> 6) ? wsum1 : 0);
    rowOff[t] = excl;
    if (t == 127) rowOff[128] = excl + v;
    rowCur[t] = excl;
  }
  __syncthreads();
  for (int i = t; i < cnt; i += 256) {
    unsigned e = edata[s0 + i];
    unsigned r8 = e >> 24;
    if ((int)(r8 >> 7) == half) {
      int pos = atomicAdd(&rowCur[r8 & 127], 1);
      if (pos < 2048) colS[pos] = e & 0xFFFFFFu;
    }
  }
  __syncthreads();
  int g16 = t >> 4, lane16 = t & 15;
  int rowsbase = b * 256 + half * 128;
  for (int r = g16; r < 128; r += 16) {
    int grow = rowsbase + r;
    if (grow >= 2 * NN) break;
    int e0 = rowOff[r], e1 = rowOff[r + 1];
    float a0[8] = {0.f, 0.f, 0.f, 0.f, 0.f, 0.f, 0.f, 0.f};
    float a1[8] = {0.f, 0.f, 0.f, 0.f, 0.f, 0.f, 0.f, 0.f};
    int i = e0;
    for (; i + 1 < e1; i += 2) {
      unsigned c0 = colS[i], c1 = colS[i + 1];
      u16x8 v0 = *(const u16x8*)(xbD + (size_t)c0 * 256 + lane16 * 16);
      u16x8 v1 = *(const u16x8*)(xbD + (size_t)c1 * 256 + lane16 * 16);
#pragma unroll
      for (int j = 0; j < 8; ++j) { a0[j] += bf2f(v0[j]); a1[j] += bf2f(v1[j]); }
    }
    if (i < e1) {
      unsigned c0 = colS[i];
      u16x8 v0 = *(const u16x8*)(xbD + (size_t)c0 * 256 + lane16 * 16);
#pragma unroll
      for (int j = 0; j < 8; ++j) a0[j] += bf2f(v0[j]);
    }
    u16x8 hv;
#pragma unroll
    for (int j = 0; j < 8; ++j) hv[j] = f2bf(a0[j] + a1[j]);
    if (grow < NN)
      *(u16x8*)(aggLb + (size_t)grow * DD + lane16 * 8) = hv;
    else
      *(u16x8*)(outD + (size_t)(grow - NN) * 512 + 256 + lane16 * 16) = hv;
  }
}

// ---------------------------------------------------------------- GEMM 256-row tile, 512 threads (8 waves), BK=32
// R20: halves block count (391) -> B re-read halved, barrier amortization x2,
// occupancy 2 blocks/CU x 8 waves = 16 waves/CU. LDS 56KB.
__global__ __launch_bounds__(512, 4) void gemm_k(
    const char* __restrict__ xbD, unsigned short* __restrict__ aggLb,
    const char* __restrict__ outD, const unsigned short* __restrict__ Bw,
    float* __restrict__ stats) {
  __shared__ unsigned short Asm[2][256 * 32];  // 16KB each
  __shared__ unsigned short Bsm[2][128 * 32];  // 8KB each
  __shared__ float red[8][256];                // 8KB
  int t = threadIdx.x, wave = t >> 6, lane = t & 63;
  int row0 = blockIdx.x * 256;

  f32x4 acc[2][8];
#pragma unroll
  for (int mi = 0; mi < 2; ++mi)
#pragma unroll
    for (int ni = 0; ni < 8; ++ni) acc[mi][ni] = (f32x4){0.f, 0.f, 0.f, 0.f};

  // rows are 64B (4 chunks of 16B); swizzle chunk c -> c ^ ((r>>1)&3).
  // LDS dest linear: 16B/thread-slot. A: 1024 slots, 2 iters of 512 threads,
  // base short idx (i*512+wave*64)*8. B: 512 slots, 1 iter, base (wave*64)*8.
  auto STAGE = [&](int s, int b) {
#pragma unroll
    for (int i = 0; i < 2; ++i) {
      int flat = t + i * 512, r = flat >> 2, c = flat & 3;
      int cs = c ^ ((r >> 1) & 3);
      int rr = row0 + r; rr = (rr < NN) ? rr : (NN - 1);
      const char* src;
      if (s < 4)      src = xbD + (size_t)rr * 256 + (s & 3) * 64 + cs * 16;
      else if (s < 8) src = (const char*)aggLb + (size_t)rr * 256 + (s - 4) * 64 + cs * 16;
      else            src = outD + (size_t)rr * 512 + 256 + (s - 8) * 64 + cs * 16;
      gld16(src, &Asm[b][(size_t)(i * 512 + wave * 64) * 8]);
    }
    {
      int flat = t, n = flat >> 2, c = flat & 3;
      int cs = c ^ ((n >> 1) & 3);
      const char* src = (const char*)Bw + (size_t)n * 768 + s * 64 + cs * 16;
      gld16(src, &Bsm[b][(size_t)(wave * 64) * 8]);
    }
  };

  auto COMPUTE = [&](int b) {
    int mr = lane & 15, kq = lane >> 4;
    int r0 = wave * 32 + mr, r1 = r0 + 16;   // wave in 0..7 -> rows 0..255
    bf16x8 a0 = *(const bf16x8*)&Asm[b][((size_t)r0 * 4 + (kq ^ ((r0 >> 1) & 3))) * 8];
    bf16x8 a1 = *(const bf16x8*)&Asm[b][((size_t)r1 * 4 + (kq ^ ((r1 >> 1) & 3))) * 8];
#pragma unroll
    for (int ni = 0; ni < 8; ++ni) {
      int nr = ni * 16 + mr;
      bf16x8 bb = *(const bf16x8*)&Bsm[b][((size_t)nr * 4 + (kq ^ ((nr >> 1) & 3))) * 8];
      acc[0][ni] = __builtin_amdgcn_mfma_f32_16x16x32_bf16(a0, bb, acc[0][ni], 0, 0, 0);
      acc[1][ni] = __builtin_amdgcn_mfma_f32_16x16x32_bf16(a1, bb, acc[1][ni], 0, 0, 0);
    }
  };

  STAGE(0, 0);
  __syncthreads();
#pragma unroll
  for (int s = 0; s < 12; ++s) {
    int b = s & 1;
    if (s < 11) STAGE(s + 1, b ^ 1);
    COMPUTE(b);
    __syncthreads();
  }

  // epilogue: C/D layout col=lane&15, row=(lane>>4)*4+reg; C -> bf16 over aggLb (own rows)
  int colbase = lane & 15, rbase = (lane >> 4) * 4;
#pragma unroll
  for (int ni = 0; ni < 8; ++ni) {
    int col = ni * 16 + colbase;
    float s = 0.f, q = 0.f;
#pragma unroll
    for (int mi = 0; mi < 2; ++mi)
#pragma unroll
      for (int r = 0; r < 4; ++r) {
        int row = row0 + wave * 32 + mi * 16 + rbase + r;
        float v = acc[mi][ni][r];
        if (row < NN) {
          aggLb[(size_t)row * DD + col] = f2bf(v);
          s += v; q += v * v;
        }
      }
    s += __shfl_xor(s, 16); s += __shfl_xor(s, 32);
    q += __shfl_xor(q, 16); q += __shfl_xor(q, 32);
    if (lane < 16) { red[wave][col] = s; red[wave][128 + col] = q; }
  }
  __syncthreads();
  if (t < 256) {
    float v = 0.f;
#pragma unroll
    for (int w = 0; w < 8; ++w) v += red[w][t];
    atomicAdd(&stats[t], v);
  }
}

// ---------------------------------------------------------------- BN finalize + apply + ReLU (fused)
__global__ __launch_bounds__(256) void bn_relu_k(const unsigned short* __restrict__ Cb,
                                                 const float* __restrict__ stats,
                                                 const float* __restrict__ gamma,
                                                 const float* __restrict__ beta,
                                                 float* __restrict__ out) {
  __shared__ float sc[128], sh[128];
  int t = threadIdx.x;
  if (t < 128) {
    float mean = stats[t] * (1.f / NN);
    float var = stats[DD + t] * (1.f / NN) - mean * mean;
    float inv = rsqrtf(var + BN_EPS);
    float s = gamma[t] * inv;
    sc[t] = s;
    sh[t] = beta[t] - mean * s;
  }
  __syncthreads();
  int i8 = blockIdx.x * 256 + t;  // 1.6M exact
  int row = i8 >> 4, c = i8 & 15;
  u16x8 h = *(const u16x8*)(Cb + (size_t)row * DD + c * 8);
  int f0 = c * 8;
  f32x4 o0, o1;
#pragma unroll
  for (int j = 0; j < 4; ++j) {
    o0[j] = fmaxf(bf2f(h[j]) * sc[f0 + j] + sh[f0 + j], 0.f);
    o1[j] = fmaxf(bf2f(h[4 + j]) * sc[f0 + 4 + j] + sh[f0 + 4 + j], 0.f);
  }
  float* dst = out + (size_t)row * DD + f0;
  *(f32x4*)dst = o0;
  *(f32x4*)(dst + 4) = o1;
}

// ---------------------------------------------------------------- launch
extern "C" void kernel_launch(void* const* d_in, const int* in_sizes, int n_in,
                              void* d_out, int out_size, void* d_ws, size_t ws_size,
                              hipStream_t stream) {
  const float* x     = (const float*)d_in[0];
  const int*   lei   = (const int*)d_in[1];
  const int*   gei   = (const int*)d_in[2];
  const float* W1    = (const float*)d_in[3];
  const float* W2L   = (const float*)d_in[4];
  const float* W2G   = (const float*)d_in[5];
  const float* gamma = (const float*)d_in[6];
  const float* beta  = (const float*)d_in[7];
  float* out = (float*)d_out;
  char* outD = (char*)d_out;  // aggG lives in odd 256B halves of out rows

  char* w = (char*)d_ws;
  size_t o = 0;
  char* xbD = (char*)(w + o); o += (size_t)NN * 256;                           // 25.6MB dense bf16 x
  unsigned short* aggLb = (unsigned short*)(w + o); o += (size_t)NN * DD * 2;  // 25.6MB (later holds bf16 C)
  unsigned* edata = (unsigned*)(w + o); o += (size_t)NBK * SLOT * 4;           // 9.41MB
  int* gCur = (int*)(w + o); o += 1024 * 4;
  unsigned short* Bw = (unsigned short*)(w + o); o += (size_t)DD * 384 * 2;    // 96KB
  float* stats = (float*)(w + o); o += 1024;   // total ~60.71MB

  init_k<<<5, 256, 0, stream>>>(gCur, stats);

  int nbc = (2 * EE + CHUNK - 1) / CHUNK;  // 245
  bscat_k<<<nbc, 1024, 0, stream>>>(lei, gei, gCur, edata, x, xbD, W1, W2L, W2G, Bw);
  bgather_k<<<1568, 256, 0, stream>>>(xbD, gCur, edata, aggLb, outD);

  gemm_k<<<(NN + 255) / 256, 512, 0, stream>>>(xbD, aggLb, outD, Bw, stats);
  bn_relu_k<<<(NN * DD / 8) / 256, 256, 0, stream>>>(aggLb, stats, gamma, beta, out);
}